// Round 16
// baseline (834.981 us; speedup 1.0000x reference)
//
#include <hip/hip_runtime.h>
#include <math.h>

namespace {

constexpr int Bn = 8, Sn = 1024, Dn = 768, Hn = 12, DHn = 64, Fn = 3072;
constexpr int Mrows = Bn * Sn;  // 8192 token rows

typedef __attribute__((ext_vector_type(8))) short bfrag;   // 8 bf16 = 4 VGPR
typedef __attribute__((ext_vector_type(4))) float f4acc;   // 4 f32 acc
typedef __attribute__((ext_vector_type(4))) float f4v;     // native float4
typedef __attribute__((ext_vector_type(8))) ushort u8v;    // 8 bf16 packed

typedef const __attribute__((address_space(1))) unsigned int* gas_t;
typedef __attribute__((address_space(3))) unsigned int* las_t;

__device__ __forceinline__ void gload16(const ushort* g, ushort* l) {
  __builtin_amdgcn_global_load_lds((gas_t)g, (las_t)l, 16, 0, 0);
}

__device__ __forceinline__ f4acc mfma16(bfrag a, bfrag b, f4acc c) {
  return __builtin_amdgcn_mfma_f32_16x16x32_bf16(a, b, c, 0, 0, 0);
}

// split fp32 -> bf16 hi + bf16 lo (truncation; residual ~2^-16 rel)
__device__ __forceinline__ void bsplit(float x, ushort& h, ushort& l) {
  union { float f; unsigned u; } a; a.f = x;
  const ushort hi = (ushort)(a.u >> 16);
  union { unsigned u; float f; } hf; hf.u = (unsigned)hi << 16;
  union { float f; unsigned u; } b; b.f = x - hf.f;
  h = hi; l = (ushort)(b.u >> 16);
}

__device__ __forceinline__ ushort rne_bf16(float x) {
  union { float f; unsigned u; } a; a.f = x;
  const unsigned r = a.u + 0x7FFF + ((a.u >> 16) & 1);
  return (ushort)(r >> 16);
}

__device__ __forceinline__ float bf2f(ushort x) {
  union { unsigned u; float f; } t; t.u = ((unsigned)x) << 16;
  return t.f;
}

// ---------------------------------------------------------------------------
// Fused prologue: ONE launch for input split + all 6 weight transpose-splits.
//   blocks [0, 2048)        : x fp32 -> x_hi/x_lo (grid-stride)
//   blocks [2048, 2048+1728): 64x64 transpose-split tiles of the 6 weights
// ---------------------------------------------------------------------------
__global__ __launch_bounds__(256) void prologue_kernel(
    const float4* __restrict__ X, ushort* __restrict__ x_hi,
    ushort* __restrict__ x_lo, const float* __restrict__ Wq,
    ushort* __restrict__ wqt_hi, ushort* __restrict__ wqt_lo,
    const float* __restrict__ Wk, ushort* __restrict__ wkt_hi,
    ushort* __restrict__ wkt_lo, const float* __restrict__ Wv,
    ushort* __restrict__ wvt_hi, ushort* __restrict__ wvt_lo,
    const float* __restrict__ Wo_, ushort* __restrict__ wot_hi,
    ushort* __restrict__ wot_lo, const float* __restrict__ W1_,
    ushort* __restrict__ w1t_hi, ushort* __restrict__ w1t_lo,
    const float* __restrict__ W2_, ushort* __restrict__ w2t_hi,
    ushort* __restrict__ w2t_lo) {
  __shared__ float t[64][65];
  const int tid = threadIdx.x;
  int bid = blockIdx.x;

  if (bid < 2048) {
    // ---- split_rows ----
    const int n4 = Mrows * Dn / 4;
    int i = bid * 256 + tid;
    const int stride = 2048 * 256;
    for (; i < n4; i += stride) {
      const float4 v = X[i];
      ushort h0, l0, h1, l1, h2, l2, h3, l3;
      bsplit(v.x, h0, l0); bsplit(v.y, h1, l1);
      bsplit(v.z, h2, l2); bsplit(v.w, h3, l3);
      ushort4 hv; hv.x = h0; hv.y = h1; hv.z = h2; hv.w = h3;
      ushort4 lv; lv.x = l0; lv.y = l1; lv.z = l2; lv.w = l3;
      *(ushort4*)&x_hi[(size_t)i * 4] = hv;
      *(ushort4*)&x_lo[(size_t)i * 4] = lv;
    }
    return;
  }
  bid -= 2048;

  // ---- transpose-split task table ----
  const float* W;
  ushort* Th;
  ushort* Tl;
  int K, N, bx, by;
  if (bid < 144) {
    W = Wq; Th = wqt_hi; Tl = wqt_lo; K = Dn; N = Dn; bx = bid % 12; by = bid / 12;
  } else if (bid < 288) {
    bid -= 144;
    W = Wk; Th = wkt_hi; Tl = wkt_lo; K = Dn; N = Dn; bx = bid % 12; by = bid / 12;
  } else if (bid < 432) {
    bid -= 288;
    W = Wv; Th = wvt_hi; Tl = wvt_lo; K = Dn; N = Dn; bx = bid % 12; by = bid / 12;
  } else if (bid < 576) {
    bid -= 432;
    W = Wo_; Th = wot_hi; Tl = wot_lo; K = Dn; N = Dn; bx = bid % 12; by = bid / 12;
  } else if (bid < 1152) {
    bid -= 576;
    W = W1_; Th = w1t_hi; Tl = w1t_lo; K = Dn; N = Fn; bx = bid % 48; by = bid / 48;
  } else {
    bid -= 1152;
    W = W2_; Th = w2t_hi; Tl = w2t_lo; K = Fn; N = Dn; bx = bid % 12; by = bid / 12;
  }

  const int k0 = by * 64, n0 = bx * 64;
  const int c = tid & 63, rg = tid >> 6;
#pragma unroll
  for (int rr = 0; rr < 16; ++rr) {
    const int r = rg * 16 + rr;
    t[r][c] = W[(size_t)(k0 + r) * N + n0 + c];
  }
  __syncthreads();
#pragma unroll
  for (int rr = 0; rr < 16; ++rr) {
    const int n = rg * 16 + rr;
    const float x = t[c][n];
    ushort h16, l16;
    bsplit(x, h16, l16);
    const size_t o = (size_t)(n0 + n) * K + k0 + c;
    Th[o] = h16;
    Tl[o] = l16;
  }
}

// ---------------------------------------------------------------------------
// bf16 split MFMA GEMM: C = epi(A @ B^T + bias [+ res]); 128x128, BK=32.
// ASPLIT=true: 3-pass (Ah.Bh + Ah.Bl + Al.Bh); false: 2-pass (Ah.Bh + Ah.Bl).
// MODE 0: QKV (2-pass: output bf16 rounding dominates) -> q plain;
//         k/v XOR-pre-swizzled 16B chunks for attn staging.
// MODE 1: Wo  (+res, fp32 C + RNE bf16 hi out)
// MODE 2: W1  (erf-GELU, RNE bf16 out, N=3072)
// MODE 3: W2  (+res, fp32 C)
// ---------------------------------------------------------------------------
template <int MODE, bool ASPLIT>
__global__ __launch_bounds__(256) void mfma_gemm(
    const ushort* __restrict__ Ah, const ushort* __restrict__ Al,
    const ushort* __restrict__ B0h, const ushort* __restrict__ B0l,
    const ushort* __restrict__ B1h, const ushort* __restrict__ B1l,
    const ushort* __restrict__ B2h, const ushort* __restrict__ B2l,
    const float* __restrict__ bias0, const float* __restrict__ bias1,
    const float* __restrict__ bias2, const float* __restrict__ res,
    float* __restrict__ C0, ushort* __restrict__ Chi,
    ushort* __restrict__ U0, ushort* __restrict__ U1,
    ushort* __restrict__ U2, int Kd) {
  constexpr int NARR = ASPLIT ? 4 : 3;  // 0=Ah 1=Bh 2=Bl [3=Al]
  __shared__ ushort lds[NARR][4096];    // 8 KB each

  const int tid = threadIdx.x;
  const int w = tid >> 6, l = tid & 63;
  const int wm = w >> 1, wn = w & 1;
  const int r16 = l & 15, kg = l >> 4;
  const int bn = blockIdx.x, bm = blockIdx.y;

  const ushort* Bh = B0h;
  const ushort* Bl = B0l;
  const float* bias = bias0;
  ushort* Uout = U0;
  int sel = 0;
  int colBase = bn * 128, bRow0 = bn * 128;
  if (MODE == 0) {
    sel = bn / 6;
    Bh = sel == 0 ? B0h : sel == 1 ? B1h : B2h;
    Bl = sel == 0 ? B0l : sel == 1 ? B1l : B2l;
    bias = sel == 0 ? bias0 : sel == 1 ? bias1 : bias2;
    Uout = sel == 0 ? U0 : sel == 1 ? U1 : U2;
    colBase = (bn % 6) * 128;
    bRow0 = colBase;
  }
  const int aRow0 = bm * 128;
  const int N = (MODE == 2) ? Fn : Dn;

  f4acc acc[4][4] = {};

  for (int k0 = 0; k0 < Kd; k0 += 32) {
    __syncthreads();
#pragma unroll
    for (int ii = 0; ii < 2; ++ii) {
      const int row = ii * 64 + l;
      const size_t aoff = (size_t)(aRow0 + row) * Kd + k0 + w * 8;
      const size_t boff = (size_t)(bRow0 + row) * Kd + k0 + w * 8;
      const int ldsOff = (w * 128 + ii * 64) * 8;
      gload16(Ah + aoff, &lds[0][ldsOff]);
      gload16(Bh + boff, &lds[1][ldsOff]);
      gload16(Bl + boff, &lds[2][ldsOff]);
      if (ASPLIT) gload16(Al + aoff, &lds[NARR - 1][ldsOff]);
    }
    __syncthreads();

    bfrag ah[4], al[4], bh[4], bl[4];
#pragma unroll
    for (int m = 0; m < 4; ++m) {
      const int p = (kg * 128 + wm * 64 + m * 16 + r16) * 8;
      ah[m] = *(const bfrag*)&lds[0][p];
      if (ASPLIT) al[m] = *(const bfrag*)&lds[NARR - 1][p];
    }
#pragma unroll
    for (int n = 0; n < 4; ++n) {
      const int p = (kg * 128 + wn * 64 + n * 16 + r16) * 8;
      bh[n] = *(const bfrag*)&lds[1][p];
      bl[n] = *(const bfrag*)&lds[2][p];
    }
#pragma unroll
    for (int m = 0; m < 4; ++m)
#pragma unroll
      for (int n = 0; n < 4; ++n) {
        acc[m][n] = mfma16(ah[m], bh[n], acc[m][n]);
        acc[m][n] = mfma16(ah[m], bl[n], acc[m][n]);
        if (ASPLIT) acc[m][n] = mfma16(al[m], bh[n], acc[m][n]);
      }
  }

  float bc[4];
#pragma unroll
  for (int n = 0; n < 4; ++n) bc[n] = bias[colBase + wn * 64 + n * 16 + r16];

#pragma unroll
  for (int m = 0; m < 4; ++m)
#pragma unroll
    for (int e = 0; e < 4; ++e) {
      const int grow = aRow0 + wm * 64 + m * 16 + (l >> 4) * 4 + e;
#pragma unroll
      for (int n = 0; n < 4; ++n) {
        const int gcol = colBase + wn * 64 + n * 16 + r16;
        const size_t o = (size_t)grow * N + gcol;
        float v = acc[m][n][e] + bc[n];
        if (MODE == 0) {
          const ushort rb = rne_bf16(v);
          if (sel == 0) {
            Uout[o] = rb;  // q plain
          } else {
            // k/v: XOR-swizzle 16B chunks within each head-row.
            // key: k -> j&7, v -> (j>>3)&7.
            const int d = gcol & 63, hh = gcol >> 6;
            const int key = (sel == 1) ? (grow & 7) : ((grow >> 3) & 7);
            const size_t o2 = (size_t)grow * Dn + hh * DHn +
                              ((((d >> 3) ^ key)) << 3) + (d & 7);
            Uout[o2] = rb;
          }
        } else if (MODE == 1) {
          v += res[o];
          C0[o] = v;
          Chi[o] = rne_bf16(v);  // RNE single-operand for 2-pass W1
        } else if (MODE == 2) {
          v = 0.5f * v * (1.f + erff(v * 0.70710678118654752f));
          Chi[o] = rne_bf16(v);
        } else {  // MODE 3
          v += res[o];
          C0[o] = v;
        }
      }
    }
}

// ---------------------------------------------------------------------------
// Flash-style MFMA attention v7: v5 + adjoin/mask DIRECT-TO-REG with one-jt
// prefetch (T14). AdjS LDS deleted -> 36.4 KB -> 4 blocks/CU (16 waves).
// Adjoin consumer reads are 64B-coalesced per quarter-wave; prefetch issued
// right after the stage barrier so HBM latency hides under QK+exp+PV.
// Everything else identical to proven v5 (f32 adjoin math, same rounding).
// ---------------------------------------------------------------------------
__global__ __launch_bounds__(256, 4) void attn_kernel(
    const ushort* __restrict__ q_hi, const ushort* __restrict__ k_sw,
    const ushort* __restrict__ v_sw, const float* __restrict__ mask,
    const float* __restrict__ adjoin, float* __restrict__ attn,
    ushort* __restrict__ ctx_hi) {
  __shared__ __align__(16) char sm[37248];
  char* Ks = sm;                           // [128][64] bf16, key r&7      16KB
  char* Vs = sm + 16384;                   // [128][64] bf16, key (r>>3)&7 16KB
  char* Ps = sm + 32768;                   // [16][128] bf16, key r&7       4KB
  float* rsumLds = (float*)(sm + 36864);   // [4][16]
  float* invLds = (float*)(sm + 37120);    // [16]

  const int tid = threadIdx.x;
  const int w = tid >> 6, l = tid & 63;
  const int l4 = l & 15, lg = l >> 4;
  const int i0 = blockIdx.x * 16;
  const int bh = blockIdx.y;
  const int b = bh / Hn, h = bh % Hn;

  // ---- Q frags (plain layout): row i0+l4, k-slice kk*32+lg*8 ----
  bfrag qa[2];
#pragma unroll
  for (int kk = 0; kk < 2; ++kk)
    qa[kk] = *(const bfrag*)(q_hi + (size_t)(b * Sn + i0 + l4) * Dn + h * DHn +
                             kk * 32 + lg * 8);

  const size_t kvHead = (size_t)b * Sn * Dn + h * DHn;
  const size_t attn_base = ((size_t)bh * Sn + i0) * Sn;

  // per-lane score columns for the two n-subtiles
  const int jl0 = 32 * w + l4, jl1 = 32 * w + 16 + l4;

  // per-lane adjoin row bases (rows lg*4+e); reads are 64B-coalesced in l4
  const float* adjR[4];
#pragma unroll
  for (int e = 0; e < 4; ++e)
    adjR[e] = adjoin + (size_t)(b * Sn + i0 + lg * 4 + e) * Sn;

  // ---- prologue prefetch: adjoin + mask for jt=0 ----
  float pfA[4], pfB[4];
#pragma unroll
  for (int e = 0; e < 4; ++e) {
    pfA[e] = adjR[e][jl0];
    pfB[e] = adjR[e][jl1];
  }
  float pm0 = mask[b * Sn + jl0], pm1 = mask[b * Sn + jl1];

  // ================= MAIN LOOP (single pass) =================
  u8v p_reg[8];       // unnormalized exp, bf16: [jt]{e: col jl0, 4+e: jl1}
  float rsP[4] = {};  // per-lane rowsum partials
  f4acc apv = {};     // UNNORMALIZED PV accumulator

#pragma unroll
  for (int jt = 0; jt < 8; ++jt) {
    const int j0 = jt * 128;
    __syncthreads();  // prev-iter LDS readers done
#pragma unroll
    for (int u = 0; u < 4; ++u) {
      const int idx = u * 256 + w * 64 + l;
      const int r = idx >> 3, s = idx & 7;
      const size_t rowOff = kvHead + (size_t)(j0 + r) * Dn + s * 8;
      gload16(k_sw + rowOff, (ushort*)(Ks + u * 4096 + w * 1024));
      gload16(v_sw + rowOff, (ushort*)(Vs + u * 4096 + w * 1024));
    }
    __syncthreads();  // K/V ready (vmcnt drained)

    // consume this jt's prefetched adjoin/mask; issue next jt's prefetch
    float cA[4], cB[4];
#pragma unroll
    for (int e = 0; e < 4; ++e) { cA[e] = pfA[e]; cB[e] = pfB[e]; }
    const float mk0 = pm0 * (-1e9f), mk1 = pm1 * (-1e9f);
    if (jt < 7) {
      const int jn = j0 + 128;
#pragma unroll
      for (int e = 0; e < 4; ++e) {
        pfA[e] = adjR[e][jn + jl0];
        pfB[e] = adjR[e][jn + jl1];
      }
      pm0 = mask[b * Sn + jn + jl0];
      pm1 = mask[b * Sn + jn + jl1];
    }

    f4acc s0 = {}, s1 = {};
#pragma unroll
    for (int kk = 0; kk < 2; ++kk) {
      const int cb = kk * 64 + lg * 16;
      const bfrag k0 = *(const bfrag*)(Ks + jl0 * 128 + (cb ^ ((jl0 & 7) << 4)));
      const bfrag k1 = *(const bfrag*)(Ks + jl1 * 128 + (cb ^ ((jl1 & 7) << 4)));
      s0 = mfma16(qa[kk], k0, s0);
      s1 = mfma16(qa[kk], k1, s1);
    }
#pragma unroll
    for (int e = 0; e < 4; ++e) {
      const int i = lg * 4 + e;
      const float ev0 = __expf(s0[e] * 0.125f + mk0 + cA[e]);
      const float ev1 = __expf(s1[e] * 0.125f + mk1 + cB[e]);
      rsP[e] += ev0 + ev1;
      const ushort b0 = rne_bf16(ev0), b1 = rne_bf16(ev1);
      p_reg[jt][e] = b0;
      p_reg[jt][4 + e] = b1;
      *(ushort*)(Ps + i * 256 + ((jl0 * 2) ^ ((i & 7) << 4))) = b0;
      *(ushort*)(Ps + i * 256 + ((jl1 * 2) ^ ((i & 7) << 4))) = b1;
    }
    __syncthreads();  // P ready

    // ---- PV (unnormalized): wave owns d-strip [16w,16w+16) ----
#pragma unroll
    for (int kk = 0; kk < 4; ++kk) {
      const int cb = kk * 64 + lg * 16;
      const bfrag pa =
          *(const bfrag*)(Ps + l4 * 256 + (cb ^ ((l4 & 7) << 4)));
      bfrag vb;
#pragma unroll
      for (int e = 0; e < 8; ++e) {
        const int j = kk * 32 + lg * 8 + e;
        vb[e] = *(const short*)(Vs + j * 128 +
                                (((16 * w + l4) * 2) ^ (((j >> 3) & 7) << 4)));
      }
      apv = mfma16(pa, vb, apv);
    }
  }

  // ---- rowsum reduce -> inv ----
#pragma unroll
  for (int e = 0; e < 4; ++e) {
    float t = rsP[e];
    t += __shfl_xor(t, 1);
    t += __shfl_xor(t, 2);
    t += __shfl_xor(t, 4);
    t += __shfl_xor(t, 8);
    if (l4 == 0) rsumLds[w * 16 + lg * 4 + e] = t;
  }
  __syncthreads();
  if (tid < 16)
    invLds[tid] = 1.0f / (rsumLds[tid] + rsumLds[16 + tid] + rsumLds[32 + tid] +
                          rsumLds[48 + tid]);
  __syncthreads();
  float inv_e[4];
#pragma unroll
  for (int e = 0; e < 4; ++e) inv_e[e] = invLds[lg * 4 + e];

  // ================= WRITEBACK PHASE (normalized attn) =================
  const int r2 = tid >> 4, c2 = tid & 15;
#pragma unroll
  for (int jt = 0; jt < 8; ++jt) {
    const int j0 = jt * 128;
    __syncthreads();  // protect Ps from previous iteration's readers
#pragma unroll
    for (int e = 0; e < 4; ++e) {
      const int i = lg * 4 + e;
      const float p0 = bf2f(p_reg[jt][e]) * inv_e[e];
      const float p1 = bf2f(p_reg[jt][4 + e]) * inv_e[e];
      *(ushort*)(Ps + i * 256 + ((jl0 * 2) ^ ((i & 7) << 4))) = rne_bf16(p0);
      *(ushort*)(Ps + i * 256 + ((jl1 * 2) ^ ((i & 7) << 4))) = rne_bf16(p1);
    }
    __syncthreads();  // normalized P ready
    const bfrag pb =
        *(const bfrag*)(Ps + r2 * 256 + ((c2 * 16) ^ ((r2 & 7) << 4)));
    f4v f0, f1;
    f0.x = bf2f((ushort)pb[0]); f0.y = bf2f((ushort)pb[1]);
    f0.z = bf2f((ushort)pb[2]); f0.w = bf2f((ushort)pb[3]);
    f1.x = bf2f((ushort)pb[4]); f1.y = bf2f((ushort)pb[5]);
    f1.z = bf2f((ushort)pb[6]); f1.w = bf2f((ushort)pb[7]);
    float* gp = attn + attn_base + (size_t)r2 * Sn + j0 + c2 * 8;
    *(f4v*)gp = f0;
    *(f4v*)(gp + 4) = f1;
  }

  // ---- ctx epilogue: scale by inv, RNE bf16 (hi-only) ----
#pragma unroll
  for (int e = 0; e < 4; ++e) {
    const int i = lg * 4 + e;
    const size_t o = (size_t)(b * Sn + i0 + i) * Dn + h * DHn + 16 * w + l4;
    ctx_hi[o] = rne_bf16(apv[e] * inv_e[e]);
  }
}

// ---------------------------------------------------------------------------
// LayerNorm over last dim (768), one block per row.
// ---------------------------------------------------------------------------
__global__ __launch_bounds__(256) void ln_kernel(
    const float* __restrict__ xin, const float* __restrict__ gamma,
    const float* __restrict__ beta, float* __restrict__ out) {
  const int row = blockIdx.x;
  const float* xr = xin + (size_t)row * Dn;
  const int tid = threadIdx.x;
  const float v0 = xr[tid];
  const float v1 = xr[tid + 256];
  const float v2 = xr[tid + 512];
  float s = v0 + v1 + v2;
  float s2 = v0 * v0 + v1 * v1 + v2 * v2;
#pragma unroll
  for (int off = 32; off > 0; off >>= 1) {
    s += __shfl_xor(s, off);
    s2 += __shfl_xor(s2, off);
  }
  __shared__ float red[2][4];
  const int w = tid >> 6, l = tid & 63;
  if (l == 0) { red[0][w] = s; red[1][w] = s2; }
  __syncthreads();
  s = red[0][0] + red[0][1] + red[0][2] + red[0][3];
  s2 = red[1][0] + red[1][1] + red[1][2] + red[1][3];
  const float mu = s * (1.f / 768.f);
  const float var = s2 * (1.f / 768.f) - mu * mu;
  const float inv = 1.0f / sqrtf(var + 1e-6f);
  out[(size_t)row * Dn + tid] = (v0 - mu) * inv * gamma[tid] + beta[tid];
  out[(size_t)row * Dn + tid + 256] =
      (v1 - mu) * inv * gamma[tid + 256] + beta[tid + 256];
  out[(size_t)row * Dn + tid + 512] =
      (v2 - mu) * inv * gamma[tid + 512] + beta[tid + 512];
}

}  // namespace

extern "C" void kernel_launch(void* const* d_in, const int* in_sizes, int n_in,
                              void* d_out, int out_size, void* d_ws,
                              size_t ws_size, hipStream_t stream) {
  const float* x = (const float*)d_in[0];
  const float* mask = (const float*)d_in[2];
  const float* adjoin = (const float*)d_in[3];
  const float* Wq = (const float*)d_in[4];
  const float* bq = (const float*)d_in[5];
  const float* Wk = (const float*)d_in[6];
  const float* bk = (const float*)d_in[7];
  const float* Wv = (const float*)d_in[8];
  const float* bv = (const float*)d_in[9];
  const float* Wo = (const float*)d_in[10];
  const float* bo = (const float*)d_in[11];
  const float* W1 = (const float*)d_in[12];
  const float* b1 = (const float*)d_in[13];
  const float* W2 = (const float*)d_in[14];
  const float* b2 = (const float*)d_in[15];
  const float* gamma2 = (const float*)d_in[16];
  const float* beta2 = (const float*)d_in[17];

  float* out2 = (float*)d_out;               // [B,S,D]
  float* attn = out2 + (size_t)Mrows * Dn;   // [B,H,S,S]

  // ---- workspace layout (bytes) ----
  char* ws = (char*)d_ws;
  const size_t BFS = (size_t)Mrows * Dn * 2;   // 12,582,912 (bf16 token map)
  const size_t F32S = (size_t)Mrows * Dn * 4;  // 25,165,824
  ushort* q_hi = (ushort*)(ws);
  ushort* k_sw = (ushort*)(ws + BFS);
  ushort* v_sw = (ushort*)(ws + 2 * BFS);
  ushort* ctx_hi = (ushort*)(ws + 3 * BFS + F32S);
  float* out1 = (float*)(ws + 5 * BFS + F32S);
  ushort* out1_hi = (ushort*)(ws);                  // over q_hi (dead)
  ushort* h_hi = (ushort*)(ws + 2 * BFS);           // over v_sw..ctx_hi
  const size_t WDD = (size_t)Dn * Dn * 2;           // 1.18 MB
  const size_t WDF = (size_t)Dn * Fn * 2;           // 4.72 MB
  char* wsW = ws + 5 * BFS + 2 * F32S;
  ushort* wot_hi = (ushort*)(wsW);
  ushort* wot_lo = (ushort*)(wsW + WDD);

  // ---- d_out scratch: out2 region dead until ln (step 8) ----
  char* o2r = (char*)out2;
  ushort* w1t_hi = (ushort*)(o2r);
  ushort* w1t_lo = (ushort*)(o2r + WDF);
  ushort* w2t_hi = (ushort*)(o2r + 2 * WDF);
  ushort* w2t_lo = (ushort*)(o2r + 3 * WDF);

  // ---- d_out scratch: attn region dead until attn_kernel (step 3) ----
  char* scr = (char*)attn;
  ushort* x_hi = (ushort*)(scr);
  ushort* x_lo = (ushort*)(scr + BFS);
  ushort* wqt_hi = (ushort*)(scr + 2 * BFS);
  ushort* wqt_lo = (ushort*)(scr + 2 * BFS + WDD);
  ushort* wkt_hi = (ushort*)(scr + 2 * BFS + 2 * WDD);
  ushort* wkt_lo = (ushort*)(scr + 2 * BFS + 3 * WDD);
  ushort* wvt_hi = (ushort*)(scr + 2 * BFS + 4 * WDD);
  ushort* wvt_lo = (ushort*)(scr + 2 * BFS + 5 * WDD);

  const dim3 blk(256);

  // 1) fused prologue: input split + all weight transpose-splits (1 launch)
  prologue_kernel<<<dim3(2048 + 1728), blk, 0, stream>>>(
      (const float4*)x, x_hi, x_lo, Wq, wqt_hi, wqt_lo, Wk, wkt_hi, wkt_lo,
      Wv, wvt_hi, wvt_lo, Wo, wot_hi, wot_lo, W1, w1t_hi, w1t_lo, W2, w2t_hi,
      w2t_lo);

  // 2) fused QKV projection (2-pass: bf16 output rounding dominates)
  mfma_gemm<0, false><<<dim3(18, 64), blk, 0, stream>>>(
      x_hi, nullptr, wqt_hi, wqt_lo, wkt_hi, wkt_lo, wvt_hi, wvt_lo, bq, bk,
      bv, nullptr, nullptr, nullptr, q_hi, k_sw, v_sw, Dn);

  // 3) flash attention v7 (adjoin direct-to-reg prefetch; 4 blocks/CU)
  attn_kernel<<<dim3(Sn / 16, Bn * Hn), blk, 0, stream>>>(
      q_hi, k_sw, v_sw, mask, adjoin, attn, ctx_hi);

  // 5) out1 = x + ctx @ Wo + bo  (2-pass; + RNE bf16 out)
  mfma_gemm<1, false><<<dim3(6, 64), blk, 0, stream>>>(
      ctx_hi, nullptr, wot_hi, wot_lo, nullptr, nullptr, nullptr, nullptr, bo,
      nullptr, nullptr, x, out1, out1_hi, nullptr, nullptr, nullptr, Dn);

  // 6) h_hi = bf16(gelu(out1 @ W1 + b1))  (2-pass)
  mfma_gemm<2, false><<<dim3(24, 64), blk, 0, stream>>>(
      out1_hi, nullptr, w1t_hi, w1t_lo, nullptr, nullptr, nullptr, nullptr, b1,
      nullptr, nullptr, nullptr, nullptr, h_hi, nullptr, nullptr, nullptr, Dn);

  // 7) out1 += h @ W2 + b2 (in place; 2-pass)
  mfma_gemm<3, false><<<dim3(6, 64), blk, 0, stream>>>(
      h_hi, nullptr, w2t_hi, w2t_lo, nullptr, nullptr, nullptr, nullptr, b2,
      nullptr, nullptr, out1, out1, nullptr, nullptr, nullptr, nullptr, Fn);

  // 8) out2 = layernorm(out1)
  ln_kernel<<<dim3(Mrows), blk, 0, stream>>>(out1, gamma2, beta2, out2);
}

// Round 17
// 768.352 us; speedup vs baseline: 1.0867x; 1.0867x over previous
//
#include <hip/hip_runtime.h>
#include <math.h>

namespace {

constexpr int Bn = 8, Sn = 1024, Dn = 768, Hn = 12, DHn = 64, Fn = 3072;
constexpr int Mrows = Bn * Sn;  // 8192 token rows

typedef __attribute__((ext_vector_type(8))) short bfrag;   // 8 bf16 = 4 VGPR
typedef __attribute__((ext_vector_type(4))) float f4acc;   // 4 f32 acc
typedef __attribute__((ext_vector_type(4))) float f4v;     // native float4
typedef __attribute__((ext_vector_type(8))) ushort u8v;    // 8 bf16 packed

typedef const __attribute__((address_space(1))) unsigned int* gas_t;
typedef __attribute__((address_space(3))) unsigned int* las_t;

__device__ __forceinline__ void gload16(const ushort* g, ushort* l) {
  __builtin_amdgcn_global_load_lds((gas_t)g, (las_t)l, 16, 0, 0);
}

__device__ __forceinline__ f4acc mfma16(bfrag a, bfrag b, f4acc c) {
  return __builtin_amdgcn_mfma_f32_16x16x32_bf16(a, b, c, 0, 0, 0);
}

// split fp32 -> bf16 hi + bf16 lo (truncation; residual ~2^-16 rel)
__device__ __forceinline__ void bsplit(float x, ushort& h, ushort& l) {
  union { float f; unsigned u; } a; a.f = x;
  const ushort hi = (ushort)(a.u >> 16);
  union { unsigned u; float f; } hf; hf.u = (unsigned)hi << 16;
  union { float f; unsigned u; } b; b.f = x - hf.f;
  h = hi; l = (ushort)(b.u >> 16);
}

__device__ __forceinline__ ushort rne_bf16(float x) {
  union { float f; unsigned u; } a; a.f = x;
  const unsigned r = a.u + 0x7FFF + ((a.u >> 16) & 1);
  return (ushort)(r >> 16);
}

__device__ __forceinline__ float bf2f(ushort x) {
  union { unsigned u; float f; } t; t.u = ((unsigned)x) << 16;
  return t.f;
}

// ---------------------------------------------------------------------------
// Fused prologue: ONE launch for input split + all 6 weight transpose-splits.
//   blocks [0, 2048)        : x fp32 -> x_hi (lo plane dead: QKV is 1-pass)
//   blocks [2048, 2048+1728): 64x64 transpose-split tiles of the 6 weights
//   (q/k/v weights: hi only; Wo/W1/W2: hi+lo for 2-pass GEMMs)
// ---------------------------------------------------------------------------
__global__ __launch_bounds__(256) void prologue_kernel(
    const float4* __restrict__ X, ushort* __restrict__ x_hi,
    ushort* __restrict__ x_lo, const float* __restrict__ Wq,
    ushort* __restrict__ wqt_hi, ushort* __restrict__ wqt_lo,
    const float* __restrict__ Wk, ushort* __restrict__ wkt_hi,
    ushort* __restrict__ wkt_lo, const float* __restrict__ Wv,
    ushort* __restrict__ wvt_hi, ushort* __restrict__ wvt_lo,
    const float* __restrict__ Wo_, ushort* __restrict__ wot_hi,
    ushort* __restrict__ wot_lo, const float* __restrict__ W1_,
    ushort* __restrict__ w1t_hi, ushort* __restrict__ w1t_lo,
    const float* __restrict__ W2_, ushort* __restrict__ w2t_hi,
    ushort* __restrict__ w2t_lo) {
  __shared__ float t[64][65];
  const int tid = threadIdx.x;
  int bid = blockIdx.x;

  if (bid < 2048) {
    // ---- x -> bf16 hi (RNE-equivalent trunc-hi kept: matches prior rounds) ----
    const int n4 = Mrows * Dn / 4;
    int i = bid * 256 + tid;
    const int stride = 2048 * 256;
    for (; i < n4; i += stride) {
      const float4 v = X[i];
      ushort h0, l0, h1, l1, h2, l2, h3, l3;
      bsplit(v.x, h0, l0); bsplit(v.y, h1, l1);
      bsplit(v.z, h2, l2); bsplit(v.w, h3, l3);
      ushort4 hv; hv.x = h0; hv.y = h1; hv.z = h2; hv.w = h3;
      *(ushort4*)&x_hi[(size_t)i * 4] = hv;
    }
    return;
  }
  bid -= 2048;

  // ---- transpose-split task table (Tl == nullptr -> hi only) ----
  const float* W;
  ushort* Th;
  ushort* Tl;
  int K, N, bx, by;
  if (bid < 144) {
    W = Wq; Th = wqt_hi; Tl = nullptr; K = Dn; N = Dn; bx = bid % 12; by = bid / 12;
  } else if (bid < 288) {
    bid -= 144;
    W = Wk; Th = wkt_hi; Tl = nullptr; K = Dn; N = Dn; bx = bid % 12; by = bid / 12;
  } else if (bid < 432) {
    bid -= 288;
    W = Wv; Th = wvt_hi; Tl = nullptr; K = Dn; N = Dn; bx = bid % 12; by = bid / 12;
  } else if (bid < 576) {
    bid -= 432;
    W = Wo_; Th = wot_hi; Tl = wot_lo; K = Dn; N = Dn; bx = bid % 12; by = bid / 12;
  } else if (bid < 1152) {
    bid -= 576;
    W = W1_; Th = w1t_hi; Tl = w1t_lo; K = Dn; N = Fn; bx = bid % 48; by = bid / 48;
  } else {
    bid -= 1152;
    W = W2_; Th = w2t_hi; Tl = w2t_lo; K = Fn; N = Dn; bx = bid % 12; by = bid / 12;
  }

  const int k0 = by * 64, n0 = bx * 64;
  const int c = tid & 63, rg = tid >> 6;
#pragma unroll
  for (int rr = 0; rr < 16; ++rr) {
    const int r = rg * 16 + rr;
    t[r][c] = W[(size_t)(k0 + r) * N + n0 + c];
  }
  __syncthreads();
#pragma unroll
  for (int rr = 0; rr < 16; ++rr) {
    const int n = rg * 16 + rr;
    const float x = t[c][n];
    ushort h16, l16;
    bsplit(x, h16, l16);
    const size_t o = (size_t)(n0 + n) * K + k0 + c;
    Th[o] = h16;
    if (Tl) Tl[o] = l16;
  }
}

// ---------------------------------------------------------------------------
// bf16 split MFMA GEMM: C = epi(A @ B^T + bias [+ res]); 128x128, BK=32.
// PASSES: 1 = Ah.Bh; 2 = + Ah.Bl; 3 = + Al.Bh.
// MODE 0: QKV (1-pass) -> q plain; k/v XOR-pre-swizzled 16B chunks.
// MODE 1: Wo  (2-pass, +res, fp32 C + RNE bf16 hi out)
// MODE 2: W1  (2-pass, erf-GELU, RNE bf16 out, N=3072)
// MODE 3: W2  (2-pass, +res, fp32 C)
// ---------------------------------------------------------------------------
template <int MODE, int PASSES>
__global__ __launch_bounds__(256) void mfma_gemm(
    const ushort* __restrict__ Ah, const ushort* __restrict__ Al,
    const ushort* __restrict__ B0h, const ushort* __restrict__ B0l,
    const ushort* __restrict__ B1h, const ushort* __restrict__ B1l,
    const ushort* __restrict__ B2h, const ushort* __restrict__ B2l,
    const float* __restrict__ bias0, const float* __restrict__ bias1,
    const float* __restrict__ bias2, const float* __restrict__ res,
    float* __restrict__ C0, ushort* __restrict__ Chi,
    ushort* __restrict__ U0, ushort* __restrict__ U1,
    ushort* __restrict__ U2, int Kd) {
  constexpr int NARR = (PASSES == 3) ? 4 : (PASSES == 2 ? 3 : 2);
  __shared__ ushort lds[NARR][4096];  // 8 KB each: 0=Ah 1=Bh [2=Bl] [3=Al]

  const int tid = threadIdx.x;
  const int w = tid >> 6, l = tid & 63;
  const int wm = w >> 1, wn = w & 1;
  const int r16 = l & 15, kg = l >> 4;
  const int bn = blockIdx.x, bm = blockIdx.y;

  ushort* ldsBl = lds[(PASSES >= 2) ? (NARR == 4 ? 2 : NARR - 1) : 0];
  ushort* ldsAl = lds[(PASSES == 3) ? NARR - 1 : 0];

  const ushort* Bh = B0h;
  const ushort* Bl = B0l;
  const float* bias = bias0;
  ushort* Uout = U0;
  int sel = 0;
  int colBase = bn * 128, bRow0 = bn * 128;
  if (MODE == 0) {
    sel = bn / 6;
    Bh = sel == 0 ? B0h : sel == 1 ? B1h : B2h;
    Bl = sel == 0 ? B0l : sel == 1 ? B1l : B2l;
    bias = sel == 0 ? bias0 : sel == 1 ? bias1 : bias2;
    Uout = sel == 0 ? U0 : sel == 1 ? U1 : U2;
    colBase = (bn % 6) * 128;
    bRow0 = colBase;
  }
  const int aRow0 = bm * 128;
  const int N = (MODE == 2) ? Fn : Dn;

  f4acc acc[4][4] = {};

  for (int k0 = 0; k0 < Kd; k0 += 32) {
    __syncthreads();
#pragma unroll
    for (int ii = 0; ii < 2; ++ii) {
      const int row = ii * 64 + l;
      const size_t aoff = (size_t)(aRow0 + row) * Kd + k0 + w * 8;
      const size_t boff = (size_t)(bRow0 + row) * Kd + k0 + w * 8;
      const int ldsOff = (w * 128 + ii * 64) * 8;
      gload16(Ah + aoff, &lds[0][ldsOff]);
      gload16(Bh + boff, &lds[1][ldsOff]);
      if (PASSES >= 2) gload16(Bl + boff, &ldsBl[ldsOff]);
      if (PASSES == 3) gload16(Al + aoff, &ldsAl[ldsOff]);
    }
    __syncthreads();

    bfrag ah[4], al[4], bh[4], bl[4];
#pragma unroll
    for (int m = 0; m < 4; ++m) {
      const int p = (kg * 128 + wm * 64 + m * 16 + r16) * 8;
      ah[m] = *(const bfrag*)&lds[0][p];
      if (PASSES == 3) al[m] = *(const bfrag*)&ldsAl[p];
    }
#pragma unroll
    for (int n = 0; n < 4; ++n) {
      const int p = (kg * 128 + wn * 64 + n * 16 + r16) * 8;
      bh[n] = *(const bfrag*)&lds[1][p];
      if (PASSES >= 2) bl[n] = *(const bfrag*)&ldsBl[p];
    }
#pragma unroll
    for (int m = 0; m < 4; ++m)
#pragma unroll
      for (int n = 0; n < 4; ++n) {
        acc[m][n] = mfma16(ah[m], bh[n], acc[m][n]);
        if (PASSES >= 2) acc[m][n] = mfma16(ah[m], bl[n], acc[m][n]);
        if (PASSES == 3) acc[m][n] = mfma16(al[m], bh[n], acc[m][n]);
      }
  }

  float bc[4];
#pragma unroll
  for (int n = 0; n < 4; ++n) bc[n] = bias[colBase + wn * 64 + n * 16 + r16];

#pragma unroll
  for (int m = 0; m < 4; ++m)
#pragma unroll
    for (int e = 0; e < 4; ++e) {
      const int grow = aRow0 + wm * 64 + m * 16 + (l >> 4) * 4 + e;
#pragma unroll
      for (int n = 0; n < 4; ++n) {
        const int gcol = colBase + wn * 64 + n * 16 + r16;
        const size_t o = (size_t)grow * N + gcol;
        float v = acc[m][n][e] + bc[n];
        if (MODE == 0) {
          const ushort rb = rne_bf16(v);
          if (sel == 0) {
            Uout[o] = rb;  // q plain
          } else {
            // k/v: XOR-swizzle 16B chunks within each head-row.
            // key: k -> j&7, v -> (j>>3)&7.
            const int d = gcol & 63, hh = gcol >> 6;
            const int key = (sel == 1) ? (grow & 7) : ((grow >> 3) & 7);
            const size_t o2 = (size_t)grow * Dn + hh * DHn +
                              ((((d >> 3) ^ key)) << 3) + (d & 7);
            Uout[o2] = rb;
          }
        } else if (MODE == 1) {
          v += res[o];
          C0[o] = v;
          Chi[o] = rne_bf16(v);
        } else if (MODE == 2) {
          v = 0.5f * v * (1.f + erff(v * 0.70710678118654752f));
          Chi[o] = rne_bf16(v);
        } else {  // MODE 3
          v += res[o];
          C0[o] = v;
        }
      }
    }
}

// ---------------------------------------------------------------------------
// Flash-style MFMA attention v8: proven v5 main loop + CONSOLIDATED writeback.
// After the main loop Ks/Vs (32 KB) are dead; all 8 j-tiles of normalized P
// are written there once, then 8 coalesced store iterations run with no
// further barriers (2 barriers total vs 16 in v5). Arithmetic identical.
// ---------------------------------------------------------------------------
__global__ __launch_bounds__(256, 3) void attn_kernel(
    const ushort* __restrict__ q_hi, const ushort* __restrict__ k_sw,
    const ushort* __restrict__ v_sw, const float* __restrict__ mask,
    const float* __restrict__ adjoin, float* __restrict__ attn,
    ushort* __restrict__ ctx_hi) {
  __shared__ __align__(16) char sm[45440];
  char* Ks = sm;                           // [128][64] bf16, key r&7      16KB
  char* Vs = sm + 16384;                   // [128][64] bf16, key (r>>3)&7 16KB
  char* AdjS = sm + 32768;                 // [16][128] f32, key r&7        8KB
  char* Ps = sm + 40960;                   // [16][128] bf16, key r&7       4KB
  float* rsumLds = (float*)(sm + 45056);   // [4][16]
  float* invLds = (float*)(sm + 45312);    // [16]

  const int tid = threadIdx.x;
  const int w = tid >> 6, l = tid & 63;
  const int l4 = l & 15, lg = l >> 4;
  const int i0 = blockIdx.x * 16;
  const int bh = blockIdx.y;
  const int b = bh / Hn, h = bh % Hn;

  // ---- Q frags (plain layout): row i0+l4, k-slice kk*32+lg*8 ----
  bfrag qa[2];
#pragma unroll
  for (int kk = 0; kk < 2; ++kk)
    qa[kk] = *(const bfrag*)(q_hi + (size_t)(b * Sn + i0 + l4) * Dn + h * DHn +
                             kk * 32 + lg * 8);

  const size_t kvHead = (size_t)b * Sn * Dn + h * DHn;
  const size_t attn_base = ((size_t)bh * Sn + i0) * Sn;

  // per-lane score columns for the two n-subtiles
  const int jl0 = 32 * w + l4, jl1 = 32 * w + 16 + l4;

  // ================= MAIN LOOP (single pass) =================
  u8v p_reg[8];       // unnormalized exp, bf16: [jt]{e: col jl0, 4+e: jl1}
  float rsP[4] = {};  // per-lane rowsum partials
  f4acc apv = {};     // UNNORMALIZED PV accumulator

#pragma unroll
  for (int jt = 0; jt < 8; ++jt) {
    const int j0 = jt * 128;
    __syncthreads();  // prev-iter LDS readers done
#pragma unroll
    for (int u = 0; u < 4; ++u) {
      const int idx = u * 256 + w * 64 + l;
      const int r = idx >> 3, s = idx & 7;
      const size_t rowOff = kvHead + (size_t)(j0 + r) * Dn + s * 8;
      gload16(k_sw + rowOff, (ushort*)(Ks + u * 4096 + w * 1024));
      gload16(v_sw + rowOff, (ushort*)(Vs + u * 4096 + w * 1024));
    }
    float4 ar[2];
#pragma unroll
    for (int u = 0; u < 2; ++u) {
      const int idx = tid + 256 * u;
      const int r = idx >> 5, f = idx & 31;
      ar[u] = *(const float4*)(adjoin + (size_t)(b * Sn + i0 + r) * Sn + j0 +
                               f * 4);
    }
    const float mk0 = mask[b * Sn + j0 + jl0] * (-1e9f);
    const float mk1 = mask[b * Sn + j0 + jl1] * (-1e9f);
#pragma unroll
    for (int u = 0; u < 2; ++u) {
      const int idx = tid + 256 * u;
      const int r = idx >> 5, f = idx & 31;
      *(float4*)(AdjS + r * 512 + ((f * 16) ^ ((r & 7) << 4))) = ar[u];
    }
    __syncthreads();  // K/V (vmcnt drained) + Adj ready

    f4acc s0 = {}, s1 = {};
#pragma unroll
    for (int kk = 0; kk < 2; ++kk) {
      const int cb = kk * 64 + lg * 16;
      const bfrag k0 = *(const bfrag*)(Ks + jl0 * 128 + (cb ^ ((jl0 & 7) << 4)));
      const bfrag k1 = *(const bfrag*)(Ks + jl1 * 128 + (cb ^ ((jl1 & 7) << 4)));
      s0 = mfma16(qa[kk], k0, s0);
      s1 = mfma16(qa[kk], k1, s1);
    }
#pragma unroll
    for (int e = 0; e < 4; ++e) {
      const int i = lg * 4 + e;
      const float a0 =
          *(const float*)(AdjS + i * 512 + ((jl0 * 4) ^ ((i & 7) << 4)));
      const float a1 =
          *(const float*)(AdjS + i * 512 + ((jl1 * 4) ^ ((i & 7) << 4)));
      const float ev0 = __expf(s0[e] * 0.125f + mk0 + a0);
      const float ev1 = __expf(s1[e] * 0.125f + mk1 + a1);
      rsP[e] += ev0 + ev1;
      const ushort b0 = rne_bf16(ev0), b1 = rne_bf16(ev1);
      p_reg[jt][e] = b0;
      p_reg[jt][4 + e] = b1;
      *(ushort*)(Ps + i * 256 + ((jl0 * 2) ^ ((i & 7) << 4))) = b0;
      *(ushort*)(Ps + i * 256 + ((jl1 * 2) ^ ((i & 7) << 4))) = b1;
    }
    __syncthreads();  // P ready

    // ---- PV (unnormalized): wave owns d-strip [16w,16w+16) ----
#pragma unroll
    for (int kk = 0; kk < 4; ++kk) {
      const int cb = kk * 64 + lg * 16;
      const bfrag pa =
          *(const bfrag*)(Ps + l4 * 256 + (cb ^ ((l4 & 7) << 4)));
      bfrag vb;
#pragma unroll
      for (int e = 0; e < 8; ++e) {
        const int j = kk * 32 + lg * 8 + e;
        vb[e] = *(const short*)(Vs + j * 128 +
                                (((16 * w + l4) * 2) ^ (((j >> 3) & 7) << 4)));
      }
      apv = mfma16(pa, vb, apv);
    }
  }

  // ---- rowsum reduce -> inv ----
#pragma unroll
  for (int e = 0; e < 4; ++e) {
    float t = rsP[e];
    t += __shfl_xor(t, 1);
    t += __shfl_xor(t, 2);
    t += __shfl_xor(t, 4);
    t += __shfl_xor(t, 8);
    if (l4 == 0) rsumLds[w * 16 + lg * 4 + e] = t;
  }
  __syncthreads();  // also: all PV reads of Ks/Vs complete
  if (tid < 16)
    invLds[tid] = 1.0f / (rsumLds[tid] + rsumLds[16 + tid] + rsumLds[32 + tid] +
                          rsumLds[48 + tid]);
  __syncthreads();
  float inv_e[4];
#pragma unroll
  for (int e = 0; e < 4; ++e) inv_e[e] = invLds[lg * 4 + e];

  // ============ CONSOLIDATED WRITEBACK (2 barriers total) ============
  char* Pall = sm;  // 32 KB over dead Ks+Vs: [16 rows][1024 cols] bf16
#pragma unroll
  for (int jt = 0; jt < 8; ++jt) {
#pragma unroll
    for (int e = 0; e < 4; ++e) {
      const int i = lg * 4 + e;
      const float p0 = bf2f(p_reg[jt][e]) * inv_e[e];
      const float p1 = bf2f(p_reg[jt][4 + e]) * inv_e[e];
      const int c0 = (jt * 128 + jl0) * 2, c1 = (jt * 128 + jl1) * 2;
      *(ushort*)(Pall + i * 2048 + (c0 ^ ((i & 7) << 4))) = rne_bf16(p0);
      *(ushort*)(Pall + i * 2048 + (c1 ^ ((i & 7) << 4))) = rne_bf16(p1);
    }
  }
  __syncthreads();  // all normalized P in place
  const int r2 = tid >> 4, c2 = tid & 15;
#pragma unroll
  for (int jt = 0; jt < 8; ++jt) {
    const bfrag pb = *(const bfrag*)(
        Pall + r2 * 2048 + ((jt * 256 + c2 * 16) ^ ((r2 & 7) << 4)));
    f4v f0, f1;
    f0.x = bf2f((ushort)pb[0]); f0.y = bf2f((ushort)pb[1]);
    f0.z = bf2f((ushort)pb[2]); f0.w = bf2f((ushort)pb[3]);
    f1.x = bf2f((ushort)pb[4]); f1.y = bf2f((ushort)pb[5]);
    f1.z = bf2f((ushort)pb[6]); f1.w = bf2f((ushort)pb[7]);
    float* gp = attn + attn_base + (size_t)r2 * Sn + jt * 128 + c2 * 8;
    *(f4v*)gp = f0;
    *(f4v*)(gp + 4) = f1;
  }

  // ---- ctx epilogue: scale by inv, RNE bf16 (hi-only) ----
#pragma unroll
  for (int e = 0; e < 4; ++e) {
    const int i = lg * 4 + e;
    const size_t o = (size_t)(b * Sn + i0 + i) * Dn + h * DHn + 16 * w + l4;
    ctx_hi[o] = rne_bf16(apv[e] * inv_e[e]);
  }
}

// ---------------------------------------------------------------------------
// LayerNorm over last dim (768), one block per row.
// ---------------------------------------------------------------------------
__global__ __launch_bounds__(256) void ln_kernel(
    const float* __restrict__ xin, const float* __restrict__ gamma,
    const float* __restrict__ beta, float* __restrict__ out) {
  const int row = blockIdx.x;
  const float* xr = xin + (size_t)row * Dn;
  const int tid = threadIdx.x;
  const float v0 = xr[tid];
  const float v1 = xr[tid + 256];
  const float v2 = xr[tid + 512];
  float s = v0 + v1 + v2;
  float s2 = v0 * v0 + v1 * v1 + v2 * v2;
#pragma unroll
  for (int off = 32; off > 0; off >>= 1) {
    s += __shfl_xor(s, off);
    s2 += __shfl_xor(s2, off);
  }
  __shared__ float red[2][4];
  const int w = tid >> 6, l = tid & 63;
  if (l == 0) { red[0][w] = s; red[1][w] = s2; }
  __syncthreads();
  s = red[0][0] + red[0][1] + red[0][2] + red[0][3];
  s2 = red[1][0] + red[1][1] + red[1][2] + red[1][3];
  const float mu = s * (1.f / 768.f);
  const float var = s2 * (1.f / 768.f) - mu * mu;
  const float inv = 1.0f / sqrtf(var + 1e-6f);
  out[(size_t)row * Dn + tid] = (v0 - mu) * inv * gamma[tid] + beta[tid];
  out[(size_t)row * Dn + tid + 256] =
      (v1 - mu) * inv * gamma[tid + 256] + beta[tid + 256];
  out[(size_t)row * Dn + tid + 512] =
      (v2 - mu) * inv * gamma[tid + 512] + beta[tid + 512];
}

}  // namespace

extern "C" void kernel_launch(void* const* d_in, const int* in_sizes, int n_in,
                              void* d_out, int out_size, void* d_ws,
                              size_t ws_size, hipStream_t stream) {
  const float* x = (const float*)d_in[0];
  const float* mask = (const float*)d_in[2];
  const float* adjoin = (const float*)d_in[3];
  const float* Wq = (const float*)d_in[4];
  const float* bq = (const float*)d_in[5];
  const float* Wk = (const float*)d_in[6];
  const float* bk = (const float*)d_in[7];
  const float* Wv = (const float*)d_in[8];
  const float* bv = (const float*)d_in[9];
  const float* Wo = (const float*)d_in[10];
  const float* bo = (const float*)d_in[11];
  const float* W1 = (const float*)d_in[12];
  const float* b1 = (const float*)d_in[13];
  const float* W2 = (const float*)d_in[14];
  const float* b2 = (const float*)d_in[15];
  const float* gamma2 = (const float*)d_in[16];
  const float* beta2 = (const float*)d_in[17];

  float* out2 = (float*)d_out;               // [B,S,D]
  float* attn = out2 + (size_t)Mrows * Dn;   // [B,H,S,S]

  // ---- workspace layout (bytes) ----
  char* ws = (char*)d_ws;
  const size_t BFS = (size_t)Mrows * Dn * 2;   // 12,582,912 (bf16 token map)
  const size_t F32S = (size_t)Mrows * Dn * 4;  // 25,165,824
  ushort* q_hi = (ushort*)(ws);
  ushort* k_sw = (ushort*)(ws + BFS);
  ushort* v_sw = (ushort*)(ws + 2 * BFS);
  ushort* ctx_hi = (ushort*)(ws + 3 * BFS + F32S);
  float* out1 = (float*)(ws + 5 * BFS + F32S);
  ushort* out1_hi = (ushort*)(ws);                  // over q_hi (dead)
  ushort* h_hi = (ushort*)(ws + 2 * BFS);           // over v_sw..ctx_hi
  const size_t WDD = (size_t)Dn * Dn * 2;           // 1.18 MB
  const size_t WDF = (size_t)Dn * Fn * 2;           // 4.72 MB
  char* wsW = ws + 5 * BFS + 2 * F32S;
  ushort* wot_hi = (ushort*)(wsW);
  ushort* wot_lo = (ushort*)(wsW + WDD);

  // ---- d_out scratch: out2 region dead until ln (step 8) ----
  char* o2r = (char*)out2;
  ushort* w1t_hi = (ushort*)(o2r);
  ushort* w1t_lo = (ushort*)(o2r + WDF);
  ushort* w2t_hi = (ushort*)(o2r + 2 * WDF);
  ushort* w2t_lo = (ushort*)(o2r + 3 * WDF);

  // ---- d_out scratch: attn region dead until attn_kernel (step 3) ----
  char* scr = (char*)attn;
  ushort* x_hi = (ushort*)(scr);
  ushort* x_lo = (ushort*)(scr + BFS);
  ushort* wqt_hi = (ushort*)(scr + 2 * BFS);
  ushort* wqt_lo = (ushort*)(scr + 2 * BFS + WDD);
  ushort* wkt_hi = (ushort*)(scr + 2 * BFS + 2 * WDD);
  ushort* wkt_lo = (ushort*)(scr + 2 * BFS + 3 * WDD);
  ushort* wvt_hi = (ushort*)(scr + 2 * BFS + 4 * WDD);
  ushort* wvt_lo = (ushort*)(scr + 2 * BFS + 5 * WDD);

  const dim3 blk(256);

  // 1) fused prologue: input split + weight transpose-splits (1 launch)
  prologue_kernel<<<dim3(2048 + 1728), blk, 0, stream>>>(
      (const float4*)x, x_hi, x_lo, Wq, wqt_hi, wqt_lo, Wk, wkt_hi, wkt_lo,
      Wv, wvt_hi, wvt_lo, Wo, wot_hi, wot_lo, W1, w1t_hi, w1t_lo, W2, w2t_hi,
      w2t_lo);

  // 2) fused QKV projection (1-pass: output bf16 rounding dominates)
  mfma_gemm<0, 1><<<dim3(18, 64), blk, 0, stream>>>(
      x_hi, nullptr, wqt_hi, nullptr, wkt_hi, nullptr, wvt_hi, nullptr, bq,
      bk, bv, nullptr, nullptr, nullptr, q_hi, k_sw, v_sw, Dn);

  // 3) flash attention v8 (consolidated writeback)
  attn_kernel<<<dim3(Sn / 16, Bn * Hn), blk, 0, stream>>>(
      q_hi, k_sw, v_sw, mask, adjoin, attn, ctx_hi);

  // 5) out1 = x + ctx @ Wo + bo  (2-pass; + RNE bf16 out)
  mfma_gemm<1, 2><<<dim3(6, 64), blk, 0, stream>>>(
      ctx_hi, nullptr, wot_hi, wot_lo, nullptr, nullptr, nullptr, nullptr, bo,
      nullptr, nullptr, x, out1, out1_hi, nullptr, nullptr, nullptr, Dn);

  // 6) h_hi = bf16(gelu(out1 @ W1 + b1))  (2-pass)
  mfma_gemm<2, 2><<<dim3(24, 64), blk, 0, stream>>>(
      out1_hi, nullptr, w1t_hi, w1t_lo, nullptr, nullptr, nullptr, nullptr, b1,
      nullptr, nullptr, nullptr, nullptr, h_hi, nullptr, nullptr, nullptr, Dn);

  // 7) out1 += h @ W2 + b2 (in place; 2-pass)
  mfma_gemm<3, 2><<<dim3(6, 64), blk, 0, stream>>>(
      h_hi, nullptr, w2t_hi, w2t_lo, nullptr, nullptr, nullptr, nullptr, b2,
      nullptr, nullptr, out1, out1, nullptr, nullptr, nullptr, nullptr, Fn);

  // 8) out2 = layernorm(out1)
  ln_kernel<<<dim3(Mrows), blk, 0, stream>>>(out1, gamma2, beta2, out2);
}

// Round 18
// 747.053 us; speedup vs baseline: 1.1177x; 1.0285x over previous
//
#include <hip/hip_runtime.h>
#include <math.h>

namespace {

constexpr int Bn = 8, Sn = 1024, Dn = 768, Hn = 12, DHn = 64, Fn = 3072;
constexpr int Mrows = Bn * Sn;  // 8192 token rows

typedef __attribute__((ext_vector_type(8))) short bfrag;   // 8 bf16 = 4 VGPR
typedef __attribute__((ext_vector_type(4))) float f4acc;   // 4 f32 acc
typedef __attribute__((ext_vector_type(4))) float f4v;     // native float4
typedef __attribute__((ext_vector_type(8))) ushort u8v;    // 8 bf16 packed

typedef const __attribute__((address_space(1))) unsigned int* gas_t;
typedef __attribute__((address_space(3))) unsigned int* las_t;

__device__ __forceinline__ void gload16(const ushort* g, ushort* l) {
  __builtin_amdgcn_global_load_lds((gas_t)g, (las_t)l, 16, 0, 0);
}

__device__ __forceinline__ f4acc mfma16(bfrag a, bfrag b, f4acc c) {
  return __builtin_amdgcn_mfma_f32_16x16x32_bf16(a, b, c, 0, 0, 0);
}

// split fp32 -> bf16 hi + bf16 lo (truncation; residual ~2^-16 rel)
__device__ __forceinline__ void bsplit(float x, ushort& h, ushort& l) {
  union { float f; unsigned u; } a; a.f = x;
  const ushort hi = (ushort)(a.u >> 16);
  union { unsigned u; float f; } hf; hf.u = (unsigned)hi << 16;
  union { float f; unsigned u; } b; b.f = x - hf.f;
  h = hi; l = (ushort)(b.u >> 16);
}

__device__ __forceinline__ ushort rne_bf16(float x) {
  union { float f; unsigned u; } a; a.f = x;
  const unsigned r = a.u + 0x7FFF + ((a.u >> 16) & 1);
  return (ushort)(r >> 16);
}

__device__ __forceinline__ float bf2f(ushort x) {
  union { unsigned u; float f; } t; t.u = ((unsigned)x) << 16;
  return t.f;
}

// ---------------------------------------------------------------------------
// Fused prologue: ONE launch for input split + all 6 weight transpose-splits.
//   blocks [0, 2048)        : x fp32 -> x_hi (lo plane dead: QKV is 1-pass)
//   blocks [2048, 2048+1728): 64x64 transpose-split tiles of the 6 weights
//   (q/k/v weights: hi only; Wo/W1/W2: hi+lo for 2-pass GEMMs)
// ---------------------------------------------------------------------------
__global__ __launch_bounds__(256) void prologue_kernel(
    const float4* __restrict__ X, ushort* __restrict__ x_hi,
    ushort* __restrict__ x_lo, const float* __restrict__ Wq,
    ushort* __restrict__ wqt_hi, ushort* __restrict__ wqt_lo,
    const float* __restrict__ Wk, ushort* __restrict__ wkt_hi,
    ushort* __restrict__ wkt_lo, const float* __restrict__ Wv,
    ushort* __restrict__ wvt_hi, ushort* __restrict__ wvt_lo,
    const float* __restrict__ Wo_, ushort* __restrict__ wot_hi,
    ushort* __restrict__ wot_lo, const float* __restrict__ W1_,
    ushort* __restrict__ w1t_hi, ushort* __restrict__ w1t_lo,
    const float* __restrict__ W2_, ushort* __restrict__ w2t_hi,
    ushort* __restrict__ w2t_lo) {
  __shared__ float t[64][65];
  const int tid = threadIdx.x;
  int bid = blockIdx.x;

  if (bid < 2048) {
    // ---- x -> bf16 hi ----
    const int n4 = Mrows * Dn / 4;
    int i = bid * 256 + tid;
    const int stride = 2048 * 256;
    for (; i < n4; i += stride) {
      const float4 v = X[i];
      ushort h0, l0, h1, l1, h2, l2, h3, l3;
      bsplit(v.x, h0, l0); bsplit(v.y, h1, l1);
      bsplit(v.z, h2, l2); bsplit(v.w, h3, l3);
      ushort4 hv; hv.x = h0; hv.y = h1; hv.z = h2; hv.w = h3;
      *(ushort4*)&x_hi[(size_t)i * 4] = hv;
    }
    return;
  }
  bid -= 2048;

  // ---- transpose-split task table (Tl == nullptr -> hi only) ----
  const float* W;
  ushort* Th;
  ushort* Tl;
  int K, N, bx, by;
  if (bid < 144) {
    W = Wq; Th = wqt_hi; Tl = nullptr; K = Dn; N = Dn; bx = bid % 12; by = bid / 12;
  } else if (bid < 288) {
    bid -= 144;
    W = Wk; Th = wkt_hi; Tl = nullptr; K = Dn; N = Dn; bx = bid % 12; by = bid / 12;
  } else if (bid < 432) {
    bid -= 288;
    W = Wv; Th = wvt_hi; Tl = nullptr; K = Dn; N = Dn; bx = bid % 12; by = bid / 12;
  } else if (bid < 576) {
    bid -= 432;
    W = Wo_; Th = wot_hi; Tl = wot_lo; K = Dn; N = Dn; bx = bid % 12; by = bid / 12;
  } else if (bid < 1152) {
    bid -= 576;
    W = W1_; Th = w1t_hi; Tl = w1t_lo; K = Dn; N = Fn; bx = bid % 48; by = bid / 48;
  } else {
    bid -= 1152;
    W = W2_; Th = w2t_hi; Tl = w2t_lo; K = Fn; N = Dn; bx = bid % 12; by = bid / 12;
  }

  const int k0 = by * 64, n0 = bx * 64;
  const int c = tid & 63, rg = tid >> 6;
#pragma unroll
  for (int rr = 0; rr < 16; ++rr) {
    const int r = rg * 16 + rr;
    t[r][c] = W[(size_t)(k0 + r) * N + n0 + c];
  }
  __syncthreads();
#pragma unroll
  for (int rr = 0; rr < 16; ++rr) {
    const int n = rg * 16 + rr;
    const float x = t[c][n];
    ushort h16, l16;
    bsplit(x, h16, l16);
    const size_t o = (size_t)(n0 + n) * K + k0 + c;
    Th[o] = h16;
    if (Tl) Tl[o] = l16;
  }
}

// ---------------------------------------------------------------------------
// bf16 split MFMA GEMM: C = epi(A @ B^T + bias [+ res]); 128x128, BK=32.
// PASSES: 1 = Ah.Bh; 2 = + Ah.Bl; 3 = + Al.Bh.
// MODE 0: QKV (1-pass) -> q plain; k/v XOR-pre-swizzled 16B chunks.
// MODE 1: Wo  (2-pass, +res, fp32 C + RNE bf16 hi out)
// MODE 2: W1  (2-pass, erf-GELU, RNE bf16 out, N=3072)
// MODE 3: W2  (2-pass, +res, fp32 C)
// ---------------------------------------------------------------------------
template <int MODE, int PASSES>
__global__ __launch_bounds__(256) void mfma_gemm(
    const ushort* __restrict__ Ah, const ushort* __restrict__ Al,
    const ushort* __restrict__ B0h, const ushort* __restrict__ B0l,
    const ushort* __restrict__ B1h, const ushort* __restrict__ B1l,
    const ushort* __restrict__ B2h, const ushort* __restrict__ B2l,
    const float* __restrict__ bias0, const float* __restrict__ bias1,
    const float* __restrict__ bias2, const float* __restrict__ res,
    float* __restrict__ C0, ushort* __restrict__ Chi,
    ushort* __restrict__ U0, ushort* __restrict__ U1,
    ushort* __restrict__ U2, int Kd) {
  constexpr int NARR = (PASSES == 3) ? 4 : (PASSES == 2 ? 3 : 2);
  __shared__ ushort lds[NARR][4096];  // 8 KB each: 0=Ah 1=Bh [2=Bl] [3=Al]

  const int tid = threadIdx.x;
  const int w = tid >> 6, l = tid & 63;
  const int wm = w >> 1, wn = w & 1;
  const int r16 = l & 15, kg = l >> 4;
  const int bn = blockIdx.x, bm = blockIdx.y;

  ushort* ldsBl = lds[(PASSES >= 2) ? (NARR == 4 ? 2 : NARR - 1) : 0];
  ushort* ldsAl = lds[(PASSES == 3) ? NARR - 1 : 0];

  const ushort* Bh = B0h;
  const ushort* Bl = B0l;
  const float* bias = bias0;
  ushort* Uout = U0;
  int sel = 0;
  int colBase = bn * 128, bRow0 = bn * 128;
  if (MODE == 0) {
    sel = bn / 6;
    Bh = sel == 0 ? B0h : sel == 1 ? B1h : B2h;
    Bl = sel == 0 ? B0l : sel == 1 ? B1l : B2l;
    bias = sel == 0 ? bias0 : sel == 1 ? bias1 : bias2;
    Uout = sel == 0 ? U0 : sel == 1 ? U1 : U2;
    colBase = (bn % 6) * 128;
    bRow0 = colBase;
  }
  const int aRow0 = bm * 128;
  const int N = (MODE == 2) ? Fn : Dn;

  f4acc acc[4][4] = {};

  for (int k0 = 0; k0 < Kd; k0 += 32) {
    __syncthreads();
#pragma unroll
    for (int ii = 0; ii < 2; ++ii) {
      const int row = ii * 64 + l;
      const size_t aoff = (size_t)(aRow0 + row) * Kd + k0 + w * 8;
      const size_t boff = (size_t)(bRow0 + row) * Kd + k0 + w * 8;
      const int ldsOff = (w * 128 + ii * 64) * 8;
      gload16(Ah + aoff, &lds[0][ldsOff]);
      gload16(Bh + boff, &lds[1][ldsOff]);
      if (PASSES >= 2) gload16(Bl + boff, &ldsBl[ldsOff]);
      if (PASSES == 3) gload16(Al + aoff, &ldsAl[ldsOff]);
    }
    __syncthreads();

    bfrag ah[4], al[4], bh[4], bl[4];
#pragma unroll
    for (int m = 0; m < 4; ++m) {
      const int p = (kg * 128 + wm * 64 + m * 16 + r16) * 8;
      ah[m] = *(const bfrag*)&lds[0][p];
      if (PASSES == 3) al[m] = *(const bfrag*)&ldsAl[p];
    }
#pragma unroll
    for (int n = 0; n < 4; ++n) {
      const int p = (kg * 128 + wn * 64 + n * 16 + r16) * 8;
      bh[n] = *(const bfrag*)&lds[1][p];
      if (PASSES >= 2) bl[n] = *(const bfrag*)&ldsBl[p];
    }
#pragma unroll
    for (int m = 0; m < 4; ++m)
#pragma unroll
      for (int n = 0; n < 4; ++n) {
        acc[m][n] = mfma16(ah[m], bh[n], acc[m][n]);
        if (PASSES >= 2) acc[m][n] = mfma16(ah[m], bl[n], acc[m][n]);
        if (PASSES == 3) acc[m][n] = mfma16(al[m], bh[n], acc[m][n]);
      }
  }

  float bc[4];
#pragma unroll
  for (int n = 0; n < 4; ++n) bc[n] = bias[colBase + wn * 64 + n * 16 + r16];

#pragma unroll
  for (int m = 0; m < 4; ++m)
#pragma unroll
    for (int e = 0; e < 4; ++e) {
      const int grow = aRow0 + wm * 64 + m * 16 + (l >> 4) * 4 + e;
#pragma unroll
      for (int n = 0; n < 4; ++n) {
        const int gcol = colBase + wn * 64 + n * 16 + r16;
        const size_t o = (size_t)grow * N + gcol;
        float v = acc[m][n][e] + bc[n];
        if (MODE == 0) {
          const ushort rb = rne_bf16(v);
          if (sel == 0) {
            Uout[o] = rb;  // q plain
          } else {
            // k/v: XOR-swizzle 16B chunks within each head-row.
            // key: k -> j&7, v -> (j>>3)&7.
            const int d = gcol & 63, hh = gcol >> 6;
            const int key = (sel == 1) ? (grow & 7) : ((grow >> 3) & 7);
            const size_t o2 = (size_t)grow * Dn + hh * DHn +
                              ((((d >> 3) ^ key)) << 3) + (d & 7);
            Uout[o2] = rb;
          }
        } else if (MODE == 1) {
          v += res[o];
          C0[o] = v;
          Chi[o] = rne_bf16(v);
        } else if (MODE == 2) {
          v = 0.5f * v * (1.f + erff(v * 0.70710678118654752f));
          Chi[o] = rne_bf16(v);
        } else {  // MODE 3
          v += res[o];
          C0[o] = v;
        }
      }
    }
}

// ---------------------------------------------------------------------------
// Flash-style MFMA attention v5 (round-13 proven writeback restored):
// SINGLE PASS, P in regs; per-jt paced writeback (the barrier pacing keeps
// L2 write-combining effective — consolidated bursts measured +13% WRITE).
// ---------------------------------------------------------------------------
__global__ __launch_bounds__(256, 3) void attn_kernel(
    const ushort* __restrict__ q_hi, const ushort* __restrict__ k_sw,
    const ushort* __restrict__ v_sw, const float* __restrict__ mask,
    const float* __restrict__ adjoin, float* __restrict__ attn,
    ushort* __restrict__ ctx_hi) {
  __shared__ __align__(16) char sm[45440];
  char* Ks = sm;                           // [128][64] bf16, key r&7      16KB
  char* Vs = sm + 16384;                   // [128][64] bf16, key (r>>3)&7 16KB
  char* AdjS = sm + 32768;                 // [16][128] f32, key r&7        8KB
  char* Ps = sm + 40960;                   // [16][128] bf16, key r&7       4KB
  float* rsumLds = (float*)(sm + 45056);   // [4][16]
  float* invLds = (float*)(sm + 45312);    // [16]

  const int tid = threadIdx.x;
  const int w = tid >> 6, l = tid & 63;
  const int l4 = l & 15, lg = l >> 4;
  const int i0 = blockIdx.x * 16;
  const int bh = blockIdx.y;
  const int b = bh / Hn, h = bh % Hn;

  // ---- Q frags (plain layout): row i0+l4, k-slice kk*32+lg*8 ----
  bfrag qa[2];
#pragma unroll
  for (int kk = 0; kk < 2; ++kk)
    qa[kk] = *(const bfrag*)(q_hi + (size_t)(b * Sn + i0 + l4) * Dn + h * DHn +
                             kk * 32 + lg * 8);

  const size_t kvHead = (size_t)b * Sn * Dn + h * DHn;
  const size_t attn_base = ((size_t)bh * Sn + i0) * Sn;

  // per-lane score columns for the two n-subtiles
  const int jl0 = 32 * w + l4, jl1 = 32 * w + 16 + l4;

  // ================= MAIN LOOP (single pass) =================
  u8v p_reg[8];       // unnormalized exp, bf16: [jt]{e: col jl0, 4+e: jl1}
  float rsP[4] = {};  // per-lane rowsum partials
  f4acc apv = {};     // UNNORMALIZED PV accumulator

#pragma unroll
  for (int jt = 0; jt < 8; ++jt) {
    const int j0 = jt * 128;
    __syncthreads();  // prev-iter LDS readers done
#pragma unroll
    for (int u = 0; u < 4; ++u) {
      const int idx = u * 256 + w * 64 + l;
      const int r = idx >> 3, s = idx & 7;
      const size_t rowOff = kvHead + (size_t)(j0 + r) * Dn + s * 8;
      gload16(k_sw + rowOff, (ushort*)(Ks + u * 4096 + w * 1024));
      gload16(v_sw + rowOff, (ushort*)(Vs + u * 4096 + w * 1024));
    }
    float4 ar[2];
#pragma unroll
    for (int u = 0; u < 2; ++u) {
      const int idx = tid + 256 * u;
      const int r = idx >> 5, f = idx & 31;
      ar[u] = *(const float4*)(adjoin + (size_t)(b * Sn + i0 + r) * Sn + j0 +
                               f * 4);
    }
    const float mk0 = mask[b * Sn + j0 + jl0] * (-1e9f);
    const float mk1 = mask[b * Sn + j0 + jl1] * (-1e9f);
#pragma unroll
    for (int u = 0; u < 2; ++u) {
      const int idx = tid + 256 * u;
      const int r = idx >> 5, f = idx & 31;
      *(float4*)(AdjS + r * 512 + ((f * 16) ^ ((r & 7) << 4))) = ar[u];
    }
    __syncthreads();  // K/V (vmcnt drained) + Adj ready

    f4acc s0 = {}, s1 = {};
#pragma unroll
    for (int kk = 0; kk < 2; ++kk) {
      const int cb = kk * 64 + lg * 16;
      const bfrag k0 = *(const bfrag*)(Ks + jl0 * 128 + (cb ^ ((jl0 & 7) << 4)));
      const bfrag k1 = *(const bfrag*)(Ks + jl1 * 128 + (cb ^ ((jl1 & 7) << 4)));
      s0 = mfma16(qa[kk], k0, s0);
      s1 = mfma16(qa[kk], k1, s1);
    }
#pragma unroll
    for (int e = 0; e < 4; ++e) {
      const int i = lg * 4 + e;
      const float a0 =
          *(const float*)(AdjS + i * 512 + ((jl0 * 4) ^ ((i & 7) << 4)));
      const float a1 =
          *(const float*)(AdjS + i * 512 + ((jl1 * 4) ^ ((i & 7) << 4)));
      const float ev0 = __expf(s0[e] * 0.125f + mk0 + a0);
      const float ev1 = __expf(s1[e] * 0.125f + mk1 + a1);
      rsP[e] += ev0 + ev1;
      const ushort b0 = rne_bf16(ev0), b1 = rne_bf16(ev1);
      p_reg[jt][e] = b0;
      p_reg[jt][4 + e] = b1;
      *(ushort*)(Ps + i * 256 + ((jl0 * 2) ^ ((i & 7) << 4))) = b0;
      *(ushort*)(Ps + i * 256 + ((jl1 * 2) ^ ((i & 7) << 4))) = b1;
    }
    __syncthreads();  // P ready

    // ---- PV (unnormalized): wave owns d-strip [16w,16w+16) ----
#pragma unroll
    for (int kk = 0; kk < 4; ++kk) {
      const int cb = kk * 64 + lg * 16;
      const bfrag pa =
          *(const bfrag*)(Ps + l4 * 256 + (cb ^ ((l4 & 7) << 4)));
      bfrag vb;
#pragma unroll
      for (int e = 0; e < 8; ++e) {
        const int j = kk * 32 + lg * 8 + e;
        vb[e] = *(const short*)(Vs + j * 128 +
                                (((16 * w + l4) * 2) ^ (((j >> 3) & 7) << 4)));
      }
      apv = mfma16(pa, vb, apv);
    }
  }

  // ---- rowsum reduce -> inv ----
#pragma unroll
  for (int e = 0; e < 4; ++e) {
    float t = rsP[e];
    t += __shfl_xor(t, 1);
    t += __shfl_xor(t, 2);
    t += __shfl_xor(t, 4);
    t += __shfl_xor(t, 8);
    if (l4 == 0) rsumLds[w * 16 + lg * 4 + e] = t;
  }
  __syncthreads();
  if (tid < 16)
    invLds[tid] = 1.0f / (rsumLds[tid] + rsumLds[16 + tid] + rsumLds[32 + tid] +
                          rsumLds[48 + tid]);
  __syncthreads();
  float inv_e[4];
#pragma unroll
  for (int e = 0; e < 4; ++e) inv_e[e] = invLds[lg * 4 + e];

  // ======= WRITEBACK (per-jt paced; pacing preserves write-combining) ======
  const int r2 = tid >> 4, c2 = tid & 15;
#pragma unroll
  for (int jt = 0; jt < 8; ++jt) {
    const int j0 = jt * 128;
    __syncthreads();  // protect Ps from previous iteration's readers
#pragma unroll
    for (int e = 0; e < 4; ++e) {
      const int i = lg * 4 + e;
      const float p0 = bf2f(p_reg[jt][e]) * inv_e[e];
      const float p1 = bf2f(p_reg[jt][4 + e]) * inv_e[e];
      *(ushort*)(Ps + i * 256 + ((jl0 * 2) ^ ((i & 7) << 4))) = rne_bf16(p0);
      *(ushort*)(Ps + i * 256 + ((jl1 * 2) ^ ((i & 7) << 4))) = rne_bf16(p1);
    }
    __syncthreads();  // normalized P ready
    const bfrag pb =
        *(const bfrag*)(Ps + r2 * 256 + ((c2 * 16) ^ ((r2 & 7) << 4)));
    f4v f0, f1;
    f0.x = bf2f((ushort)pb[0]); f0.y = bf2f((ushort)pb[1]);
    f0.z = bf2f((ushort)pb[2]); f0.w = bf2f((ushort)pb[3]);
    f1.x = bf2f((ushort)pb[4]); f1.y = bf2f((ushort)pb[5]);
    f1.z = bf2f((ushort)pb[6]); f1.w = bf2f((ushort)pb[7]);
    float* gp = attn + attn_base + (size_t)r2 * Sn + j0 + c2 * 8;
    *(f4v*)gp = f0;
    *(f4v*)(gp + 4) = f1;
  }

  // ---- ctx epilogue: scale by inv, RNE bf16 (hi-only) ----
#pragma unroll
  for (int e = 0; e < 4; ++e) {
    const int i = lg * 4 + e;
    const size_t o = (size_t)(b * Sn + i0 + i) * Dn + h * DHn + 16 * w + l4;
    ctx_hi[o] = rne_bf16(apv[e] * inv_e[e]);
  }
}

// ---------------------------------------------------------------------------
// LayerNorm over last dim (768), one block per row.
// ---------------------------------------------------------------------------
__global__ __launch_bounds__(256) void ln_kernel(
    const float* __restrict__ xin, const float* __restrict__ gamma,
    const float* __restrict__ beta, float* __restrict__ out) {
  const int row = blockIdx.x;
  const float* xr = xin + (size_t)row * Dn;
  const int tid = threadIdx.x;
  const float v0 = xr[tid];
  const float v1 = xr[tid + 256];
  const float v2 = xr[tid + 512];
  float s = v0 + v1 + v2;
  float s2 = v0 * v0 + v1 * v1 + v2 * v2;
#pragma unroll
  for (int off = 32; off > 0; off >>= 1) {
    s += __shfl_xor(s, off);
    s2 += __shfl_xor(s2, off);
  }
  __shared__ float red[2][4];
  const int w = tid >> 6, l = tid & 63;
  if (l == 0) { red[0][w] = s; red[1][w] = s2; }
  __syncthreads();
  s = red[0][0] + red[0][1] + red[0][2] + red[0][3];
  s2 = red[1][0] + red[1][1] + red[1][2] + red[1][3];
  const float mu = s * (1.f / 768.f);
  const float var = s2 * (1.f / 768.f) - mu * mu;
  const float inv = 1.0f / sqrtf(var + 1e-6f);
  out[(size_t)row * Dn + tid] = (v0 - mu) * inv * gamma[tid] + beta[tid];
  out[(size_t)row * Dn + tid + 256] =
      (v1 - mu) * inv * gamma[tid + 256] + beta[tid + 256];
  out[(size_t)row * Dn + tid + 512] =
      (v2 - mu) * inv * gamma[tid + 512] + beta[tid + 512];
}

}  // namespace

extern "C" void kernel_launch(void* const* d_in, const int* in_sizes, int n_in,
                              void* d_out, int out_size, void* d_ws,
                              size_t ws_size, hipStream_t stream) {
  const float* x = (const float*)d_in[0];
  const float* mask = (const float*)d_in[2];
  const float* adjoin = (const float*)d_in[3];
  const float* Wq = (const float*)d_in[4];
  const float* bq = (const float*)d_in[5];
  const float* Wk = (const float*)d_in[6];
  const float* bk = (const float*)d_in[7];
  const float* Wv = (const float*)d_in[8];
  const float* bv = (const float*)d_in[9];
  const float* Wo = (const float*)d_in[10];
  const float* bo = (const float*)d_in[11];
  const float* W1 = (const float*)d_in[12];
  const float* b1 = (const float*)d_in[13];
  const float* W2 = (const float*)d_in[14];
  const float* b2 = (const float*)d_in[15];
  const float* gamma2 = (const float*)d_in[16];
  const float* beta2 = (const float*)d_in[17];

  float* out2 = (float*)d_out;               // [B,S,D]
  float* attn = out2 + (size_t)Mrows * Dn;   // [B,H,S,S]

  // ---- workspace layout (bytes) ----
  char* ws = (char*)d_ws;
  const size_t BFS = (size_t)Mrows * Dn * 2;   // 12,582,912 (bf16 token map)
  const size_t F32S = (size_t)Mrows * Dn * 4;  // 25,165,824
  ushort* q_hi = (ushort*)(ws);
  ushort* k_sw = (ushort*)(ws + BFS);
  ushort* v_sw = (ushort*)(ws + 2 * BFS);
  ushort* ctx_hi = (ushort*)(ws + 3 * BFS + F32S);
  float* out1 = (float*)(ws + 5 * BFS + F32S);
  ushort* out1_hi = (ushort*)(ws);                  // over q_hi (dead)
  ushort* h_hi = (ushort*)(ws + 2 * BFS);           // over v_sw..ctx_hi
  const size_t WDD = (size_t)Dn * Dn * 2;           // 1.18 MB
  const size_t WDF = (size_t)Dn * Fn * 2;           // 4.72 MB
  char* wsW = ws + 5 * BFS + 2 * F32S;
  ushort* wot_hi = (ushort*)(wsW);
  ushort* wot_lo = (ushort*)(wsW + WDD);

  // ---- d_out scratch: out2 region dead until ln (step 8) ----
  char* o2r = (char*)out2;
  ushort* w1t_hi = (ushort*)(o2r);
  ushort* w1t_lo = (ushort*)(o2r + WDF);
  ushort* w2t_hi = (ushort*)(o2r + 2 * WDF);
  ushort* w2t_lo = (ushort*)(o2r + 3 * WDF);

  // ---- d_out scratch: attn region dead until attn_kernel (step 3) ----
  char* scr = (char*)attn;
  ushort* x_hi = (ushort*)(scr);
  ushort* x_lo = (ushort*)(scr + BFS);
  ushort* wqt_hi = (ushort*)(scr + 2 * BFS);
  ushort* wqt_lo = (ushort*)(scr + 2 * BFS + WDD);
  ushort* wkt_hi = (ushort*)(scr + 2 * BFS + 2 * WDD);
  ushort* wkt_lo = (ushort*)(scr + 2 * BFS + 3 * WDD);
  ushort* wvt_hi = (ushort*)(scr + 2 * BFS + 4 * WDD);
  ushort* wvt_lo = (ushort*)(scr + 2 * BFS + 5 * WDD);

  const dim3 blk(256);

  // 1) fused prologue: input split + weight transpose-splits (1 launch)
  prologue_kernel<<<dim3(2048 + 1728), blk, 0, stream>>>(
      (const float4*)x, x_hi, x_lo, Wq, wqt_hi, wqt_lo, Wk, wkt_hi, wkt_lo,
      Wv, wvt_hi, wvt_lo, Wo, wot_hi, wot_lo, W1, w1t_hi, w1t_lo, W2, w2t_hi,
      w2t_lo);

  // 2) fused QKV projection (1-pass: output bf16 rounding dominates)
  mfma_gemm<0, 1><<<dim3(18, 64), blk, 0, stream>>>(
      x_hi, nullptr, wqt_hi, nullptr, wkt_hi, nullptr, wvt_hi, nullptr, bq,
      bk, bv, nullptr, nullptr, nullptr, q_hi, k_sw, v_sw, Dn);

  // 3) flash attention v5 (per-jt paced writeback restored)
  attn_kernel<<<dim3(Sn / 16, Bn * Hn), blk, 0, stream>>>(
      q_hi, k_sw, v_sw, mask, adjoin, attn, ctx_hi);

  // 5) out1 = x + ctx @ Wo + bo  (2-pass; + RNE bf16 out)
  mfma_gemm<1, 2><<<dim3(6, 64), blk, 0, stream>>>(
      ctx_hi, nullptr, wot_hi, wot_lo, nullptr, nullptr, nullptr, nullptr, bo,
      nullptr, nullptr, x, out1, out1_hi, nullptr, nullptr, nullptr, Dn);

  // 6) h_hi = bf16(gelu(out1 @ W1 + b1))  (2-pass)
  mfma_gemm<2, 2><<<dim3(24, 64), blk, 0, stream>>>(
      out1_hi, nullptr, w1t_hi, w1t_lo, nullptr, nullptr, nullptr, nullptr, b1,
      nullptr, nullptr, nullptr, nullptr, h_hi, nullptr, nullptr, nullptr, Dn);

  // 7) out1 += h @ W2 + b2 (in place; 2-pass)
  mfma_gemm<3, 2><<<dim3(6, 64), blk, 0, stream>>>(
      h_hi, nullptr, w2t_hi, w2t_lo, nullptr, nullptr, nullptr, nullptr, b2,
      nullptr, nullptr, out1, out1, nullptr, nullptr, nullptr, nullptr, Fn);

  // 8) out2 = layernorm(out1)
  ln_kernel<<<dim3(Mrows), blk, 0, stream>>>(out1, gamma2, beta2, out2);
}

// Round 19
// 644.712 us; speedup vs baseline: 1.2951x; 1.1587x over previous
//
#include <hip/hip_runtime.h>
#include <math.h>

namespace {

constexpr int Bn = 8, Sn = 1024, Dn = 768, Hn = 12, DHn = 64, Fn = 3072;
constexpr int Mrows = Bn * Sn;  // 8192 token rows

typedef __attribute__((ext_vector_type(8))) short bfrag;   // 8 bf16 = 4 VGPR
typedef __attribute__((ext_vector_type(4))) float f4acc;   // 4 f32 acc
typedef __attribute__((ext_vector_type(4))) float f4v;     // native float4
typedef __attribute__((ext_vector_type(8))) ushort u8v;    // 8 bf16 packed

typedef const __attribute__((address_space(1))) unsigned int* gas_t;
typedef __attribute__((address_space(3))) unsigned int* las_t;

__device__ __forceinline__ void gload16(const ushort* g, ushort* l) {
  __builtin_amdgcn_global_load_lds((gas_t)g, (las_t)l, 16, 0, 0);
}

__device__ __forceinline__ f4acc mfma16(bfrag a, bfrag b, f4acc c) {
  return __builtin_amdgcn_mfma_f32_16x16x32_bf16(a, b, c, 0, 0, 0);
}

// split fp32 -> bf16 hi + bf16 lo (truncation; residual ~2^-16 rel)
__device__ __forceinline__ void bsplit(float x, ushort& h, ushort& l) {
  union { float f; unsigned u; } a; a.f = x;
  const ushort hi = (ushort)(a.u >> 16);
  union { unsigned u; float f; } hf; hf.u = (unsigned)hi << 16;
  union { float f; unsigned u; } b; b.f = x - hf.f;
  h = hi; l = (ushort)(b.u >> 16);
}

__device__ __forceinline__ ushort rne_bf16(float x) {
  union { float f; unsigned u; } a; a.f = x;
  const unsigned r = a.u + 0x7FFF + ((a.u >> 16) & 1);
  return (ushort)(r >> 16);
}

__device__ __forceinline__ float bf2f(ushort x) {
  union { unsigned u; float f; } t; t.u = ((unsigned)x) << 16;
  return t.f;
}

// ---------------------------------------------------------------------------
// Fused prologue: ONE launch for input split + all 6 weight transposes.
//   blocks [0, 2048)        : x fp32 -> x_hi bf16
//   blocks [2048, 2048+1728): 64x64 transpose tiles, hi-only (all GEMMs
//   are now 1-pass on the B side)
// ---------------------------------------------------------------------------
__global__ __launch_bounds__(256) void prologue_kernel(
    const float4* __restrict__ X, ushort* __restrict__ x_hi,
    ushort* __restrict__ x_lo, const float* __restrict__ Wq,
    ushort* __restrict__ wqt_hi, ushort* __restrict__ wqt_lo,
    const float* __restrict__ Wk, ushort* __restrict__ wkt_hi,
    ushort* __restrict__ wkt_lo, const float* __restrict__ Wv,
    ushort* __restrict__ wvt_hi, ushort* __restrict__ wvt_lo,
    const float* __restrict__ Wo_, ushort* __restrict__ wot_hi,
    ushort* __restrict__ wot_lo, const float* __restrict__ W1_,
    ushort* __restrict__ w1t_hi, ushort* __restrict__ w1t_lo,
    const float* __restrict__ W2_, ushort* __restrict__ w2t_hi,
    ushort* __restrict__ w2t_lo) {
  __shared__ float t[64][65];
  const int tid = threadIdx.x;
  int bid = blockIdx.x;

  if (bid < 2048) {
    // ---- x -> bf16 hi ----
    const int n4 = Mrows * Dn / 4;
    int i = bid * 256 + tid;
    const int stride = 2048 * 256;
    for (; i < n4; i += stride) {
      const float4 v = X[i];
      ushort h0, l0, h1, l1, h2, l2, h3, l3;
      bsplit(v.x, h0, l0); bsplit(v.y, h1, l1);
      bsplit(v.z, h2, l2); bsplit(v.w, h3, l3);
      ushort4 hv; hv.x = h0; hv.y = h1; hv.z = h2; hv.w = h3;
      *(ushort4*)&x_hi[(size_t)i * 4] = hv;
    }
    return;
  }
  bid -= 2048;

  // ---- transpose task table (hi-only everywhere) ----
  const float* W;
  ushort* Th;
  int K, N, bx, by;
  if (bid < 144) {
    W = Wq; Th = wqt_hi; K = Dn; N = Dn; bx = bid % 12; by = bid / 12;
  } else if (bid < 288) {
    bid -= 144;
    W = Wk; Th = wkt_hi; K = Dn; N = Dn; bx = bid % 12; by = bid / 12;
  } else if (bid < 432) {
    bid -= 288;
    W = Wv; Th = wvt_hi; K = Dn; N = Dn; bx = bid % 12; by = bid / 12;
  } else if (bid < 576) {
    bid -= 432;
    W = Wo_; Th = wot_hi; K = Dn; N = Dn; bx = bid % 12; by = bid / 12;
  } else if (bid < 1152) {
    bid -= 576;
    W = W1_; Th = w1t_hi; K = Dn; N = Fn; bx = bid % 48; by = bid / 48;
  } else {
    bid -= 1152;
    W = W2_; Th = w2t_hi; K = Fn; N = Dn; bx = bid % 12; by = bid / 12;
  }

  const int k0 = by * 64, n0 = bx * 64;
  const int c = tid & 63, rg = tid >> 6;
#pragma unroll
  for (int rr = 0; rr < 16; ++rr) {
    const int r = rg * 16 + rr;
    t[r][c] = W[(size_t)(k0 + r) * N + n0 + c];
  }
  __syncthreads();
#pragma unroll
  for (int rr = 0; rr < 16; ++rr) {
    const int n = rg * 16 + rr;
    const float x = t[c][n];
    ushort h16, l16;
    bsplit(x, h16, l16);
    Th[(size_t)(n0 + n) * K + k0 + c] = h16;
  }
}

// ---------------------------------------------------------------------------
// bf16 MFMA GEMM: C = epi(A @ B^T + bias [+ res]); 128x128, BK=32.
// PASSES: 1 = Ah.Bh; 2 = + Ah.Bl; 3 = + Al.Bh.  (all dispatches now 1-pass;
// output/activation bf16 rounding dominates the dropped terms)
// MODE 0: QKV -> q plain; k/v XOR-pre-swizzled 16B chunks.
// MODE 1: Wo  (+res, fp32 C + RNE bf16 hi out)
// MODE 2: W1  (erf-GELU, RNE bf16 out, N=3072)
// MODE 3: W2  (+res, fp32 C)
// ---------------------------------------------------------------------------
template <int MODE, int PASSES>
__global__ __launch_bounds__(256) void mfma_gemm(
    const ushort* __restrict__ Ah, const ushort* __restrict__ Al,
    const ushort* __restrict__ B0h, const ushort* __restrict__ B0l,
    const ushort* __restrict__ B1h, const ushort* __restrict__ B1l,
    const ushort* __restrict__ B2h, const ushort* __restrict__ B2l,
    const float* __restrict__ bias0, const float* __restrict__ bias1,
    const float* __restrict__ bias2, const float* __restrict__ res,
    float* __restrict__ C0, ushort* __restrict__ Chi,
    ushort* __restrict__ U0, ushort* __restrict__ U1,
    ushort* __restrict__ U2, int Kd) {
  constexpr int NARR = (PASSES == 3) ? 4 : (PASSES == 2 ? 3 : 2);
  __shared__ ushort lds[NARR][4096];  // 8 KB each: 0=Ah 1=Bh [2=Bl] [3=Al]

  const int tid = threadIdx.x;
  const int w = tid >> 6, l = tid & 63;
  const int wm = w >> 1, wn = w & 1;
  const int r16 = l & 15, kg = l >> 4;
  const int bn = blockIdx.x, bm = blockIdx.y;

  ushort* ldsBl = lds[(PASSES >= 2) ? (NARR == 4 ? 2 : NARR - 1) : 0];
  ushort* ldsAl = lds[(PASSES == 3) ? NARR - 1 : 0];

  const ushort* Bh = B0h;
  const ushort* Bl = B0l;
  const float* bias = bias0;
  ushort* Uout = U0;
  int sel = 0;
  int colBase = bn * 128, bRow0 = bn * 128;
  if (MODE == 0) {
    sel = bn / 6;
    Bh = sel == 0 ? B0h : sel == 1 ? B1h : B2h;
    Bl = sel == 0 ? B0l : sel == 1 ? B1l : B2l;
    bias = sel == 0 ? bias0 : sel == 1 ? bias1 : bias2;
    Uout = sel == 0 ? U0 : sel == 1 ? U1 : U2;
    colBase = (bn % 6) * 128;
    bRow0 = colBase;
  }
  const int aRow0 = bm * 128;
  const int N = (MODE == 2) ? Fn : Dn;

  f4acc acc[4][4] = {};

  for (int k0 = 0; k0 < Kd; k0 += 32) {
    __syncthreads();
#pragma unroll
    for (int ii = 0; ii < 2; ++ii) {
      const int row = ii * 64 + l;
      const size_t aoff = (size_t)(aRow0 + row) * Kd + k0 + w * 8;
      const size_t boff = (size_t)(bRow0 + row) * Kd + k0 + w * 8;
      const int ldsOff = (w * 128 + ii * 64) * 8;
      gload16(Ah + aoff, &lds[0][ldsOff]);
      gload16(Bh + boff, &lds[1][ldsOff]);
      if (PASSES >= 2) gload16(Bl + boff, &ldsBl[ldsOff]);
      if (PASSES == 3) gload16(Al + aoff, &ldsAl[ldsOff]);
    }
    __syncthreads();

    bfrag ah[4], al[4], bh[4], bl[4];
#pragma unroll
    for (int m = 0; m < 4; ++m) {
      const int p = (kg * 128 + wm * 64 + m * 16 + r16) * 8;
      ah[m] = *(const bfrag*)&lds[0][p];
      if (PASSES == 3) al[m] = *(const bfrag*)&ldsAl[p];
    }
#pragma unroll
    for (int n = 0; n < 4; ++n) {
      const int p = (kg * 128 + wn * 64 + n * 16 + r16) * 8;
      bh[n] = *(const bfrag*)&lds[1][p];
      if (PASSES >= 2) bl[n] = *(const bfrag*)&ldsBl[p];
    }
#pragma unroll
    for (int m = 0; m < 4; ++m)
#pragma unroll
      for (int n = 0; n < 4; ++n) {
        acc[m][n] = mfma16(ah[m], bh[n], acc[m][n]);
        if (PASSES >= 2) acc[m][n] = mfma16(ah[m], bl[n], acc[m][n]);
        if (PASSES == 3) acc[m][n] = mfma16(al[m], bh[n], acc[m][n]);
      }
  }

  float bc[4];
#pragma unroll
  for (int n = 0; n < 4; ++n) bc[n] = bias[colBase + wn * 64 + n * 16 + r16];

#pragma unroll
  for (int m = 0; m < 4; ++m)
#pragma unroll
    for (int e = 0; e < 4; ++e) {
      const int grow = aRow0 + wm * 64 + m * 16 + (l >> 4) * 4 + e;
#pragma unroll
      for (int n = 0; n < 4; ++n) {
        const int gcol = colBase + wn * 64 + n * 16 + r16;
        const size_t o = (size_t)grow * N + gcol;
        float v = acc[m][n][e] + bc[n];
        if (MODE == 0) {
          const ushort rb = rne_bf16(v);
          if (sel == 0) {
            Uout[o] = rb;  // q plain
          } else {
            // k/v: XOR-swizzle 16B chunks within each head-row.
            // key: k -> j&7, v -> (j>>3)&7.
            const int d = gcol & 63, hh = gcol >> 6;
            const int key = (sel == 1) ? (grow & 7) : ((grow >> 3) & 7);
            const size_t o2 = (size_t)grow * Dn + hh * DHn +
                              ((((d >> 3) ^ key)) << 3) + (d & 7);
            Uout[o2] = rb;
          }
        } else if (MODE == 1) {
          v += res[o];
          C0[o] = v;
          Chi[o] = rne_bf16(v);
        } else if (MODE == 2) {
          v = 0.5f * v * (1.f + erff(v * 0.70710678118654752f));
          Chi[o] = rne_bf16(v);
        } else {  // MODE 3
          v += res[o];
          C0[o] = v;
        }
      }
    }
}

// ---------------------------------------------------------------------------
// Flash-style MFMA attention v5 (proven): SINGLE PASS, P in regs; per-jt
// paced writeback (pacing preserves L2 write-combining — consolidated
// bursts measured +13% WRITE).
// ---------------------------------------------------------------------------
__global__ __launch_bounds__(256, 3) void attn_kernel(
    const ushort* __restrict__ q_hi, const ushort* __restrict__ k_sw,
    const ushort* __restrict__ v_sw, const float* __restrict__ mask,
    const float* __restrict__ adjoin, float* __restrict__ attn,
    ushort* __restrict__ ctx_hi) {
  __shared__ __align__(16) char sm[45440];
  char* Ks = sm;                           // [128][64] bf16, key r&7      16KB
  char* Vs = sm + 16384;                   // [128][64] bf16, key (r>>3)&7 16KB
  char* AdjS = sm + 32768;                 // [16][128] f32, key r&7        8KB
  char* Ps = sm + 40960;                   // [16][128] bf16, key r&7       4KB
  float* rsumLds = (float*)(sm + 45056);   // [4][16]
  float* invLds = (float*)(sm + 45312);    // [16]

  const int tid = threadIdx.x;
  const int w = tid >> 6, l = tid & 63;
  const int l4 = l & 15, lg = l >> 4;
  const int i0 = blockIdx.x * 16;
  const int bh = blockIdx.y;
  const int b = bh / Hn, h = bh % Hn;

  // ---- Q frags (plain layout): row i0+l4, k-slice kk*32+lg*8 ----
  bfrag qa[2];
#pragma unroll
  for (int kk = 0; kk < 2; ++kk)
    qa[kk] = *(const bfrag*)(q_hi + (size_t)(b * Sn + i0 + l4) * Dn + h * DHn +
                             kk * 32 + lg * 8);

  const size_t kvHead = (size_t)b * Sn * Dn + h * DHn;
  const size_t attn_base = ((size_t)bh * Sn + i0) * Sn;

  // per-lane score columns for the two n-subtiles
  const int jl0 = 32 * w + l4, jl1 = 32 * w + 16 + l4;

  // ================= MAIN LOOP (single pass) =================
  u8v p_reg[8];       // unnormalized exp, bf16: [jt]{e: col jl0, 4+e: jl1}
  float rsP[4] = {};  // per-lane rowsum partials
  f4acc apv = {};     // UNNORMALIZED PV accumulator

#pragma unroll
  for (int jt = 0; jt < 8; ++jt) {
    const int j0 = jt * 128;
    __syncthreads();  // prev-iter LDS readers done
#pragma unroll
    for (int u = 0; u < 4; ++u) {
      const int idx = u * 256 + w * 64 + l;
      const int r = idx >> 3, s = idx & 7;
      const size_t rowOff = kvHead + (size_t)(j0 + r) * Dn + s * 8;
      gload16(k_sw + rowOff, (ushort*)(Ks + u * 4096 + w * 1024));
      gload16(v_sw + rowOff, (ushort*)(Vs + u * 4096 + w * 1024));
    }
    float4 ar[2];
#pragma unroll
    for (int u = 0; u < 2; ++u) {
      const int idx = tid + 256 * u;
      const int r = idx >> 5, f = idx & 31;
      ar[u] = *(const float4*)(adjoin + (size_t)(b * Sn + i0 + r) * Sn + j0 +
                               f * 4);
    }
    const float mk0 = mask[b * Sn + j0 + jl0] * (-1e9f);
    const float mk1 = mask[b * Sn + j0 + jl1] * (-1e9f);
#pragma unroll
    for (int u = 0; u < 2; ++u) {
      const int idx = tid + 256 * u;
      const int r = idx >> 5, f = idx & 31;
      *(float4*)(AdjS + r * 512 + ((f * 16) ^ ((r & 7) << 4))) = ar[u];
    }
    __syncthreads();  // K/V (vmcnt drained) + Adj ready

    f4acc s0 = {}, s1 = {};
#pragma unroll
    for (int kk = 0; kk < 2; ++kk) {
      const int cb = kk * 64 + lg * 16;
      const bfrag k0 = *(const bfrag*)(Ks + jl0 * 128 + (cb ^ ((jl0 & 7) << 4)));
      const bfrag k1 = *(const bfrag*)(Ks + jl1 * 128 + (cb ^ ((jl1 & 7) << 4)));
      s0 = mfma16(qa[kk], k0, s0);
      s1 = mfma16(qa[kk], k1, s1);
    }
#pragma unroll
    for (int e = 0; e < 4; ++e) {
      const int i = lg * 4 + e;
      const float a0 =
          *(const float*)(AdjS + i * 512 + ((jl0 * 4) ^ ((i & 7) << 4)));
      const float a1 =
          *(const float*)(AdjS + i * 512 + ((jl1 * 4) ^ ((i & 7) << 4)));
      const float ev0 = __expf(s0[e] * 0.125f + mk0 + a0);
      const float ev1 = __expf(s1[e] * 0.125f + mk1 + a1);
      rsP[e] += ev0 + ev1;
      const ushort b0 = rne_bf16(ev0), b1 = rne_bf16(ev1);
      p_reg[jt][e] = b0;
      p_reg[jt][4 + e] = b1;
      *(ushort*)(Ps + i * 256 + ((jl0 * 2) ^ ((i & 7) << 4))) = b0;
      *(ushort*)(Ps + i * 256 + ((jl1 * 2) ^ ((i & 7) << 4))) = b1;
    }
    __syncthreads();  // P ready

    // ---- PV (unnormalized): wave owns d-strip [16w,16w+16) ----
#pragma unroll
    for (int kk = 0; kk < 4; ++kk) {
      const int cb = kk * 64 + lg * 16;
      const bfrag pa =
          *(const bfrag*)(Ps + l4 * 256 + (cb ^ ((l4 & 7) << 4)));
      bfrag vb;
#pragma unroll
      for (int e = 0; e < 8; ++e) {
        const int j = kk * 32 + lg * 8 + e;
        vb[e] = *(const short*)(Vs + j * 128 +
                                (((16 * w + l4) * 2) ^ (((j >> 3) & 7) << 4)));
      }
      apv = mfma16(pa, vb, apv);
    }
  }

  // ---- rowsum reduce -> inv ----
#pragma unroll
  for (int e = 0; e < 4; ++e) {
    float t = rsP[e];
    t += __shfl_xor(t, 1);
    t += __shfl_xor(t, 2);
    t += __shfl_xor(t, 4);
    t += __shfl_xor(t, 8);
    if (l4 == 0) rsumLds[w * 16 + lg * 4 + e] = t;
  }
  __syncthreads();
  if (tid < 16)
    invLds[tid] = 1.0f / (rsumLds[tid] + rsumLds[16 + tid] + rsumLds[32 + tid] +
                          rsumLds[48 + tid]);
  __syncthreads();
  float inv_e[4];
#pragma unroll
  for (int e = 0; e < 4; ++e) inv_e[e] = invLds[lg * 4 + e];

  // ======= WRITEBACK (per-jt paced; pacing preserves write-combining) ======
  const int r2 = tid >> 4, c2 = tid & 15;
#pragma unroll
  for (int jt = 0; jt < 8; ++jt) {
    const int j0 = jt * 128;
    __syncthreads();  // protect Ps from previous iteration's readers
#pragma unroll
    for (int e = 0; e < 4; ++e) {
      const int i = lg * 4 + e;
      const float p0 = bf2f(p_reg[jt][e]) * inv_e[e];
      const float p1 = bf2f(p_reg[jt][4 + e]) * inv_e[e];
      *(ushort*)(Ps + i * 256 + ((jl0 * 2) ^ ((i & 7) << 4))) = rne_bf16(p0);
      *(ushort*)(Ps + i * 256 + ((jl1 * 2) ^ ((i & 7) << 4))) = rne_bf16(p1);
    }
    __syncthreads();  // normalized P ready
    const bfrag pb =
        *(const bfrag*)(Ps + r2 * 256 + ((c2 * 16) ^ ((r2 & 7) << 4)));
    f4v f0, f1;
    f0.x = bf2f((ushort)pb[0]); f0.y = bf2f((ushort)pb[1]);
    f0.z = bf2f((ushort)pb[2]); f0.w = bf2f((ushort)pb[3]);
    f1.x = bf2f((ushort)pb[4]); f1.y = bf2f((ushort)pb[5]);
    f1.z = bf2f((ushort)pb[6]); f1.w = bf2f((ushort)pb[7]);
    float* gp = attn + attn_base + (size_t)r2 * Sn + j0 + c2 * 8;
    *(f4v*)gp = f0;
    *(f4v*)(gp + 4) = f1;
  }

  // ---- ctx epilogue: scale by inv, RNE bf16 (hi-only) ----
#pragma unroll
  for (int e = 0; e < 4; ++e) {
    const int i = lg * 4 + e;
    const size_t o = (size_t)(b * Sn + i0 + i) * Dn + h * DHn + 16 * w + l4;
    ctx_hi[o] = rne_bf16(apv[e] * inv_e[e]);
  }
}

// ---------------------------------------------------------------------------
// LayerNorm over last dim (768), one block per row.
// ---------------------------------------------------------------------------
__global__ __launch_bounds__(256) void ln_kernel(
    const float* __restrict__ xin, const float* __restrict__ gamma,
    const float* __restrict__ beta, float* __restrict__ out) {
  const int row = blockIdx.x;
  const float* xr = xin + (size_t)row * Dn;
  const int tid = threadIdx.x;
  const float v0 = xr[tid];
  const float v1 = xr[tid + 256];
  const float v2 = xr[tid + 512];
  float s = v0 + v1 + v2;
  float s2 = v0 * v0 + v1 * v1 + v2 * v2;
#pragma unroll
  for (int off = 32; off > 0; off >>= 1) {
    s += __shfl_xor(s, off);
    s2 += __shfl_xor(s2, off);
  }
  __shared__ float red[2][4];
  const int w = tid >> 6, l = tid & 63;
  if (l == 0) { red[0][w] = s; red[1][w] = s2; }
  __syncthreads();
  s = red[0][0] + red[0][1] + red[0][2] + red[0][3];
  s2 = red[1][0] + red[1][1] + red[1][2] + red[1][3];
  const float mu = s * (1.f / 768.f);
  const float var = s2 * (1.f / 768.f) - mu * mu;
  const float inv = 1.0f / sqrtf(var + 1e-6f);
  out[(size_t)row * Dn + tid] = (v0 - mu) * inv * gamma[tid] + beta[tid];
  out[(size_t)row * Dn + tid + 256] =
      (v1 - mu) * inv * gamma[tid + 256] + beta[tid + 256];
  out[(size_t)row * Dn + tid + 512] =
      (v2 - mu) * inv * gamma[tid + 512] + beta[tid + 512];
}

}  // namespace

extern "C" void kernel_launch(void* const* d_in, const int* in_sizes, int n_in,
                              void* d_out, int out_size, void* d_ws,
                              size_t ws_size, hipStream_t stream) {
  const float* x = (const float*)d_in[0];
  const float* mask = (const float*)d_in[2];
  const float* adjoin = (const float*)d_in[3];
  const float* Wq = (const float*)d_in[4];
  const float* bq = (const float*)d_in[5];
  const float* Wk = (const float*)d_in[6];
  const float* bk = (const float*)d_in[7];
  const float* Wv = (const float*)d_in[8];
  const float* bv = (const float*)d_in[9];
  const float* Wo = (const float*)d_in[10];
  const float* bo = (const float*)d_in[11];
  const float* W1 = (const float*)d_in[12];
  const float* b1 = (const float*)d_in[13];
  const float* W2 = (const float*)d_in[14];
  const float* b2 = (const float*)d_in[15];
  const float* gamma2 = (const float*)d_in[16];
  const float* beta2 = (const float*)d_in[17];

  float* out2 = (float*)d_out;               // [B,S,D]
  float* attn = out2 + (size_t)Mrows * Dn;   // [B,H,S,S]

  // ---- workspace layout (bytes) ----
  char* ws = (char*)d_ws;
  const size_t BFS = (size_t)Mrows * Dn * 2;   // 12,582,912 (bf16 token map)
  const size_t F32S = (size_t)Mrows * Dn * 4;  // 25,165,824
  ushort* q_hi = (ushort*)(ws);
  ushort* k_sw = (ushort*)(ws + BFS);
  ushort* v_sw = (ushort*)(ws + 2 * BFS);
  ushort* ctx_hi = (ushort*)(ws + 3 * BFS + F32S);
  float* out1 = (float*)(ws + 5 * BFS + F32S);
  ushort* out1_hi = (ushort*)(ws);                  // over q_hi (dead)
  ushort* h_hi = (ushort*)(ws + 2 * BFS);           // over v_sw..ctx_hi
  const size_t WDD = (size_t)Dn * Dn * 2;           // 1.18 MB
  const size_t WDF = (size_t)Dn * Fn * 2;           // 4.72 MB
  char* wsW = ws + 5 * BFS + 2 * F32S;
  ushort* wot_hi = (ushort*)(wsW);

  // ---- d_out scratch: out2 region dead until ln (step 8) ----
  char* o2r = (char*)out2;
  ushort* w1t_hi = (ushort*)(o2r);
  ushort* w2t_hi = (ushort*)(o2r + WDF);

  // ---- d_out scratch: attn region dead until attn_kernel (step 3) ----
  char* scr = (char*)attn;
  ushort* x_hi = (ushort*)(scr);
  ushort* wqt_hi = (ushort*)(scr + 2 * BFS);
  ushort* wkt_hi = (ushort*)(scr + 2 * BFS + 2 * WDD);
  ushort* wvt_hi = (ushort*)(scr + 2 * BFS + 4 * WDD);

  const dim3 blk(256);

  // 1) fused prologue: input split + weight transposes (hi-only, 1 launch)
  prologue_kernel<<<dim3(2048 + 1728), blk, 0, stream>>>(
      (const float4*)x, x_hi, nullptr, Wq, wqt_hi, nullptr, Wk, wkt_hi,
      nullptr, Wv, wvt_hi, nullptr, Wo, wot_hi, nullptr, W1, w1t_hi, nullptr,
      W2, w2t_hi, nullptr);

  // 2) fused QKV projection (1-pass)
  mfma_gemm<0, 1><<<dim3(18, 64), blk, 0, stream>>>(
      x_hi, nullptr, wqt_hi, nullptr, wkt_hi, nullptr, wvt_hi, nullptr, bq,
      bk, bv, nullptr, nullptr, nullptr, q_hi, k_sw, v_sw, Dn);

  // 3) flash attention v5
  attn_kernel<<<dim3(Sn / 16, Bn * Hn), blk, 0, stream>>>(
      q_hi, k_sw, v_sw, mask, adjoin, attn, ctx_hi);

  // 5) out1 = x + ctx @ Wo + bo  (1-pass; + RNE bf16 out)
  mfma_gemm<1, 1><<<dim3(6, 64), blk, 0, stream>>>(
      ctx_hi, nullptr, wot_hi, nullptr, nullptr, nullptr, nullptr, nullptr,
      bo, nullptr, nullptr, x, out1, out1_hi, nullptr, nullptr, nullptr, Dn);

  // 6) h_hi = bf16(gelu(out1 @ W1 + b1))  (1-pass)
  mfma_gemm<2, 1><<<dim3(24, 64), blk, 0, stream>>>(
      out1_hi, nullptr, w1t_hi, nullptr, nullptr, nullptr, nullptr, nullptr,
      b1, nullptr, nullptr, nullptr, nullptr, h_hi, nullptr, nullptr, nullptr,
      Dn);

  // 7) out1 += h @ W2 + b2 (in place; 1-pass)
  mfma_gemm<3, 1><<<dim3(6, 64), blk, 0, stream>>>(
      h_hi, nullptr, w2t_hi, nullptr, nullptr, nullptr, nullptr, nullptr, b2,
      nullptr, nullptr, out1, out1, nullptr, nullptr, nullptr, nullptr, Fn);

  // 8) out2 = layernorm(out1)
  ln_kernel<<<dim3(Mrows), blk, 0, stream>>>(out1, gamma2, beta2, out2);
}